// Round 1
// baseline (667.202 us; speedup 1.0000x reference)
//
#include <hip/hip_runtime.h>
#include <math.h>

#define N_NODES 100000
#define N_EDGES 1600000
#define NFEAT   256
#define NHID    128
#define NHID2   64
#define NCLASS  40

// ---------------------------------------------------------------------------
// Kernel 1: CSR row_ptr from sorted edge_row via per-node lower_bound.
// row_ptr[n] = first index i with edge_row[i] >= n;  row_ptr[N] = E.
// ---------------------------------------------------------------------------
__global__ void build_rowptr(const int* __restrict__ edge_row,
                             int* __restrict__ row_ptr,
                             int n_nodes, int n_edges) {
    int n = blockIdx.x * blockDim.x + threadIdx.x;
    if (n > n_nodes) return;
    int lo = 0, hi = n_edges;
    while (lo < hi) {
        int mid = (lo + hi) >> 1;
        if (edge_row[mid] < n) lo = mid + 1; else hi = mid;
    }
    row_ptr[n] = lo;
}

// ---------------------------------------------------------------------------
// Kernel 2: f32 GEMM  C[M,N] = A[M,K] @ B[K,N]   (no bias/activation)
// BM=BN=64, BK=16, 256 threads, 4x4 per-thread register tile.
// K % 16 == 0 and N % 64 == 0 for all call sites (256/128, 128/64).
// ---------------------------------------------------------------------------
__global__ __launch_bounds__(256) void sgemm64(const float* __restrict__ A,
                                               const float* __restrict__ B,
                                               float* __restrict__ C,
                                               int M, int K, int N) {
    const int BM = 64, BN = 64, BK = 16;
    __shared__ float As[BK][BM + 1];   // +1 pad: keeps store conflicts ~4-way
    __shared__ float Bs[BK][BN];       // stores conflict-free (n = tid&63)
    int tid = threadIdx.x;
    int tx = tid & 15, ty = tid >> 4;
    int row0 = blockIdx.x * BM;
    int col0 = blockIdx.y * BN;

    float acc[4][4] = {};

    for (int k0 = 0; k0 < K; k0 += BK) {
        // load A tile (64x16), coalesced in k
        #pragma unroll
        for (int i = 0; i < 4; ++i) {
            int e = tid + i * 256;          // 0..1023
            int m = e >> 4, k = e & 15;
            int row = row0 + m;
            As[k][m] = (row < M) ? A[(size_t)row * K + k0 + k] : 0.f;
        }
        // load B tile (16x64), coalesced in n
        #pragma unroll
        for (int i = 0; i < 4; ++i) {
            int e = tid + i * 256;
            int k = e >> 6, n = e & 63;
            Bs[k][n] = B[(size_t)(k0 + k) * N + col0 + n];
        }
        __syncthreads();
        #pragma unroll
        for (int k = 0; k < BK; ++k) {
            float a[4], b[4];
            #pragma unroll
            for (int i = 0; i < 4; ++i) a[i] = As[k][ty * 4 + i];
            #pragma unroll
            for (int j = 0; j < 4; ++j) b[j] = Bs[k][tx * 4 + j];
            #pragma unroll
            for (int i = 0; i < 4; ++i)
                #pragma unroll
                for (int j = 0; j < 4; ++j)
                    acc[i][j] += a[i] * b[j];
        }
        __syncthreads();
    }

    #pragma unroll
    for (int i = 0; i < 4; ++i) {
        int row = row0 + ty * 4 + i;
        if (row < M) {
            #pragma unroll
            for (int j = 0; j < 4; ++j)
                C[(size_t)row * N + col0 + tx * 4 + j] = acc[i][j];
        }
    }
}

// ---------------------------------------------------------------------------
// Kernel 3: SpMM (CSR, one wave per destination node) + bias + relu.
// out[n,:] = relu( sum_e val[e] * sup[col[e],:]  + bias )
// D=128: 2 f32/lane; D=64: 1 f32/lane. Gathers are coalesced 256B/wave-load.
// Accumulation order == edge order (deterministic, matches segment_sum).
// ---------------------------------------------------------------------------
template <int D>
__global__ __launch_bounds__(256) void spmm_bias_relu(const float* __restrict__ sup,
                                                      const int* __restrict__ row_ptr,
                                                      const int* __restrict__ edge_col,
                                                      const float* __restrict__ edge_val,
                                                      const float* __restrict__ bias,
                                                      float* __restrict__ out,
                                                      int n_nodes) {
    int wave = threadIdx.x >> 6;
    int lane = threadIdx.x & 63;
    int node = blockIdx.x * 4 + wave;
    if (node >= n_nodes) return;

    int e0 = row_ptr[node];
    int e1 = row_ptr[node + 1];

    float acc0 = 0.f, acc1 = 0.f;
    for (int e = e0; e < e1; ++e) {
        int   c = edge_col[e];          // wave-uniform (HW broadcasts)
        float v = edge_val[e];
        const float* s = sup + (size_t)c * D;
        acc0 += v * s[lane];
        if (D == 128) acc1 += v * s[lane + 64];
    }

    float* o = out + (size_t)node * D;
    float r0 = acc0 + bias[lane];
    o[lane] = r0 > 0.f ? r0 : 0.f;
    if (D == 128) {
        float r1 = acc1 + bias[lane + 64];
        o[lane + 64] = r1 > 0.f ? r1 : 0.f;
    }
}

// ---------------------------------------------------------------------------
// Kernel 4: out = log_softmax( concat([x2, x1]) @ wl + bl )
// wl (192x40 = 30.7KB) + bl staged in LDS; one wave per node; lanes 0..39
// each own one class column; shuffle-reduce for max / sum-exp.
// ---------------------------------------------------------------------------
__global__ __launch_bounds__(256) void head_logsoftmax(const float* __restrict__ x2,
                                                       const float* __restrict__ x1,
                                                       const float* __restrict__ wl,
                                                       const float* __restrict__ bl,
                                                       float* __restrict__ out,
                                                       int n_nodes) {
    __shared__ float wls[(NHID2 + NHID) * NCLASS];   // 192*40
    __shared__ float bls[NCLASS];
    for (int i = threadIdx.x; i < (NHID2 + NHID) * NCLASS; i += 256) wls[i] = wl[i];
    if (threadIdx.x < NCLASS) bls[threadIdx.x] = bl[threadIdx.x];
    __syncthreads();

    int wave = threadIdx.x >> 6;
    int lane = threadIdx.x & 63;
    int node = blockIdx.x * 4 + wave;
    if (node >= n_nodes) return;

    const float* f2 = x2 + (size_t)node * NHID2;
    const float* f1 = x1 + (size_t)node * NHID;

    float v = -INFINITY;
    if (lane < NCLASS) {
        float dot = bls[lane];
        #pragma unroll 8
        for (int k = 0; k < NHID2; ++k) dot += f2[k] * wls[k * NCLASS + lane];
        #pragma unroll 8
        for (int k = 0; k < NHID; ++k) dot += f1[k] * wls[(NHID2 + k) * NCLASS + lane];
        v = dot;
    }

    // wave reduce: max
    float m = v;
    #pragma unroll
    for (int off = 32; off; off >>= 1) m = fmaxf(m, __shfl_xor(m, off));
    float ex = (lane < NCLASS) ? __expf(v - m) : 0.f;
    float s = ex;
    #pragma unroll
    for (int off = 32; off; off >>= 1) s += __shfl_xor(s, off);

    if (lane < NCLASS)
        out[(size_t)node * NCLASS + lane] = v - m - __logf(s);
}

// ---------------------------------------------------------------------------
extern "C" void kernel_launch(void* const* d_in, const int* in_sizes, int n_in,
                              void* d_out, int out_size, void* d_ws, size_t ws_size,
                              hipStream_t stream) {
    const float* x        = (const float*)d_in[0];
    const int*   edge_row = (const int*)d_in[1];   // JAX default x64-off -> int32
    const int*   edge_col = (const int*)d_in[2];
    const float* edge_val = (const float*)d_in[3];
    const float* w1       = (const float*)d_in[4];
    const float* b1       = (const float*)d_in[5];
    const float* w2       = (const float*)d_in[6];
    const float* b2       = (const float*)d_in[7];
    const float* wl       = (const float*)d_in[8];
    const float* bl       = (const float*)d_in[9];
    float* out = (float*)d_out;

    // workspace layout (all fully written each call before being read)
    char* ws = (char*)d_ws;
    size_t off = 0;
    int* row_ptr = (int*)(ws + off);
    off += (((size_t)(N_NODES + 1) * sizeof(int)) + 255) & ~(size_t)255;
    float* support = (float*)(ws + off);  off += (size_t)N_NODES * NHID * sizeof(float); // reused for layer2
    float* x1      = (float*)(ws + off);  off += (size_t)N_NODES * NHID * sizeof(float);
    float* x2      = (float*)(ws + off);  off += (size_t)N_NODES * NHID2 * sizeof(float);
    (void)ws_size; (void)in_sizes; (void)n_in; (void)out_size;

    build_rowptr<<<(N_NODES + 1 + 255) / 256, 256, 0, stream>>>(edge_row, row_ptr, N_NODES, N_EDGES);

    // layer 1: support = x @ w1 ; x1 = relu(spmm + b1)
    {
        dim3 g((N_NODES + 63) / 64, NHID / 64);
        sgemm64<<<g, 256, 0, stream>>>(x, w1, support, N_NODES, NFEAT, NHID);
    }
    spmm_bias_relu<NHID><<<(N_NODES + 3) / 4, 256, 0, stream>>>(
        support, row_ptr, edge_col, edge_val, b1, x1, N_NODES);

    // layer 2: support2 = x1 @ w2 ; x2 = relu(spmm + b2)   (support buffer reused)
    {
        dim3 g((N_NODES + 63) / 64, NHID2 / 64);
        sgemm64<<<g, 256, 0, stream>>>(x1, w2, support, N_NODES, NHID, NHID2);
    }
    spmm_bias_relu<NHID2><<<(N_NODES + 3) / 4, 256, 0, stream>>>(
        support, row_ptr, edge_col, edge_val, b2, x2, N_NODES);

    // head: out = log_softmax(concat([x2,x1]) @ wl + bl)
    head_logsoftmax<<<(N_NODES + 3) / 4, 256, 0, stream>>>(x2, x1, wl, bl, out, N_NODES);
}

// Round 2
// 416.535 us; speedup vs baseline: 1.6018x; 1.6018x over previous
//
#include <hip/hip_runtime.h>
#include <math.h>

#define N_NODES 100000
#define N_EDGES 1600000
#define NFEAT   256
#define NHID    128
#define NHID2   64
#define NCLASS  40
#define NCLS_P  64      // padded class dim for head GEMM

typedef __attribute__((ext_vector_type(8))) short bf16x8;
typedef __attribute__((ext_vector_type(4))) float f32x4;

static __device__ inline unsigned short f2bf(float f) {
    union { float f; unsigned u; } v; v.f = f;
    unsigned r = v.u + 0x7FFF + ((v.u >> 16) & 1);   // RNE
    return (unsigned short)(r >> 16);
}

// ---------------------------------------------------------------------------
// CSR row_ptr from sorted edge_row (lower_bound per node).
// ---------------------------------------------------------------------------
__global__ void build_rowptr(const int* __restrict__ edge_row,
                             int* __restrict__ row_ptr,
                             int n_nodes, int n_edges) {
    int n = blockIdx.x * blockDim.x + threadIdx.x;
    if (n > n_nodes) return;
    int lo = 0, hi = n_edges;
    while (lo < hi) {
        int mid = (lo + hi) >> 1;
        if (edge_row[mid] < n) lo = mid + 1; else hi = mid;
    }
    row_ptr[n] = lo;
}

// ---------------------------------------------------------------------------
// Weight prep: wt_bf16[NP][K] = transpose(w[K][N]) with zero-pad rows n>=N.
// ---------------------------------------------------------------------------
__global__ void conv_transpose_w(const float* __restrict__ w,
                                 unsigned short* __restrict__ wt,
                                 int K, int N, int NP) {
    int idx = blockIdx.x * blockDim.x + threadIdx.x;
    if (idx >= NP * K) return;
    int n = idx / K, k = idx - n * K;
    float v = (n < N) ? w[(size_t)k * N + n] : 0.f;
    wt[(size_t)n * K + k] = f2bf(v);
}

// ---------------------------------------------------------------------------
// bf16 MFMA GEMM: C[M,N] = A[M,K](f32, row stride lda) @ B[K,N]
// B given pre-transposed+bf16: Bt[N][K].  BM=128, BK=32, 256 thr = 4 waves.
// BN = N (grid.y == 1 at all call sites). K % 32 == 0.
// A converted f32->bf16 during LDS staging. LDS stride 40 bf16 (80B):
// frag ds_read_b128 bank pattern = 2-way (free).
// ---------------------------------------------------------------------------
template <int BN>
__global__ __launch_bounds__(256) void gemm_bf16(const float* __restrict__ A,
                                                 const unsigned short* __restrict__ Bt,
                                                 float* __restrict__ C,
                                                 int M, int K, int lda) {
    const int BKP = 40;                 // padded LDS row stride (bf16 elems)
    const int WN = BN / 2;              // wave n-extent (64 or 32)
    const int NF = WN / 16;             // n-frags per wave (4 or 2)
    __shared__ unsigned short As[128 * BKP];
    __shared__ unsigned short Bs[BN * BKP];

    int tid = threadIdx.x;
    int lane = tid & 63, wid = tid >> 6;
    int wr = wid >> 1, wc = wid & 1;
    int row0 = blockIdx.x * 128;

    f32x4 acc[4][NF];
    #pragma unroll
    for (int i = 0; i < 4; ++i)
        #pragma unroll
        for (int j = 0; j < NF; ++j) acc[i][j] = f32x4{0.f, 0.f, 0.f, 0.f};

    for (int k0 = 0; k0 < K; k0 += 32) {
        // stage A: 128x32 f32 -> bf16 (8 lanes per row -> 128B/row coalesced)
        #pragma unroll
        for (int i = 0; i < 4; ++i) {
            int s = tid + i * 256;            // 0..1023 slots of 4 floats
            int m = s >> 3;
            int k = (s & 7) * 4;
            int row = row0 + m;
            float4 a = (row < M) ? *(const float4*)(A + (size_t)row * lda + k0 + k)
                                 : float4{0.f, 0.f, 0.f, 0.f};
            ushort4 p; p.x = f2bf(a.x); p.y = f2bf(a.y); p.z = f2bf(a.z); p.w = f2bf(a.w);
            *(ushort4*)&As[m * BKP + k] = p;
        }
        // stage B^T tile: BN x 32 bf16 (16B per thread-slot)
        #pragma unroll
        for (int i = 0; i < (BN * 32) / (8 * 256); ++i) {
            int s = tid + i * 256;
            int n = s >> 2;
            int k = (s & 3) * 8;
            uint4 b = *(const uint4*)(Bt + (size_t)n * K + k0 + k);
            *(uint4*)&Bs[n * BKP + k] = b;
        }
        __syncthreads();

        bf16x8 af[4], bf[NF];
        #pragma unroll
        for (int mi = 0; mi < 4; ++mi)
            af[mi] = *(const bf16x8*)&As[(wr * 64 + mi * 16 + (lane & 15)) * BKP + (lane >> 4) * 8];
        #pragma unroll
        for (int ni = 0; ni < NF; ++ni)
            bf[ni] = *(const bf16x8*)&Bs[(wc * WN + ni * 16 + (lane & 15)) * BKP + (lane >> 4) * 8];
        #pragma unroll
        for (int mi = 0; mi < 4; ++mi)
            #pragma unroll
            for (int ni = 0; ni < NF; ++ni)
                acc[mi][ni] = __builtin_amdgcn_mfma_f32_16x16x32_bf16(af[mi], bf[ni], acc[mi][ni], 0, 0, 0);
        __syncthreads();
    }

    // epilogue: C/D layout col=lane&15, row=(lane>>4)*4+reg
    #pragma unroll
    for (int mi = 0; mi < 4; ++mi) {
        int rbase = row0 + wr * 64 + mi * 16 + ((lane >> 4) << 2);
        #pragma unroll
        for (int ni = 0; ni < NF; ++ni) {
            int col = wc * WN + ni * 16 + (lane & 15);
            #pragma unroll
            for (int r = 0; r < 4; ++r) {
                int row = rbase + r;
                if (row < M) C[(size_t)row * BN + col] = acc[mi][ni][r];
            }
        }
    }
}

// ---------------------------------------------------------------------------
// SpMM (CSR, one wave per dst node) + bias + relu, strided output.
// D=128: float2/lane (512B per wave gather instr); D=64: 1 f32/lane.
// Accumulation order == edge order (deterministic).
// ---------------------------------------------------------------------------
template <int D>
__global__ __launch_bounds__(256) void spmm_bias_relu(const float* __restrict__ sup,
                                                      const int* __restrict__ row_ptr,
                                                      const int* __restrict__ edge_col,
                                                      const float* __restrict__ edge_val,
                                                      const float* __restrict__ bias,
                                                      float* __restrict__ out,
                                                      int out_stride, int n_nodes) {
    int wave = threadIdx.x >> 6;
    int lane = threadIdx.x & 63;
    int node = blockIdx.x * 4 + wave;
    if (node >= n_nodes) return;

    int e0 = row_ptr[node];
    int e1 = row_ptr[node + 1];

    if (D == 128) {
        float ax = 0.f, ay = 0.f;
        for (int e = e0; e < e1; ++e) {
            int   c = edge_col[e];
            float v = edge_val[e];
            float2 s = *(const float2*)(sup + (size_t)c * 128 + 2 * lane);
            ax += v * s.x; ay += v * s.y;
        }
        float2 b = *(const float2*)(bias + 2 * lane);
        float rx = ax + b.x, ry = ay + b.y;
        float2 r; r.x = rx > 0.f ? rx : 0.f; r.y = ry > 0.f ? ry : 0.f;
        *(float2*)(out + (size_t)node * out_stride + 2 * lane) = r;
    } else {
        float a0 = 0.f;
        for (int e = e0; e < e1; ++e) {
            int   c = edge_col[e];
            float v = edge_val[e];
            a0 += v * sup[(size_t)c * 64 + lane];
        }
        float r0 = a0 + bias[lane];
        out[(size_t)node * out_stride + lane] = r0 > 0.f ? r0 : 0.f;
    }
}

// ---------------------------------------------------------------------------
// log_softmax over padded logits[node][64] (cols 0..39 valid) + bias bl.
// ---------------------------------------------------------------------------
__global__ __launch_bounds__(256) void logsm(const float* __restrict__ logits,
                                             const float* __restrict__ bl,
                                             float* __restrict__ out,
                                             int n_nodes) {
    int wave = threadIdx.x >> 6;
    int lane = threadIdx.x & 63;
    int node = blockIdx.x * 4 + wave;
    if (node >= n_nodes) return;

    float v = -INFINITY;
    if (lane < NCLASS) v = logits[(size_t)node * NCLS_P + lane] + bl[lane];

    float m = v;
    #pragma unroll
    for (int off = 32; off; off >>= 1) m = fmaxf(m, __shfl_xor(m, off));
    float ex = (lane < NCLASS) ? __expf(v - m) : 0.f;
    float s = ex;
    #pragma unroll
    for (int off = 32; off; off >>= 1) s += __shfl_xor(s, off);

    if (lane < NCLASS)
        out[(size_t)node * NCLASS + lane] = v - m - __logf(s);
}

// ---------------------------------------------------------------------------
extern "C" void kernel_launch(void* const* d_in, const int* in_sizes, int n_in,
                              void* d_out, int out_size, void* d_ws, size_t ws_size,
                              hipStream_t stream) {
    const float* x        = (const float*)d_in[0];
    const int*   edge_row = (const int*)d_in[1];
    const int*   edge_col = (const int*)d_in[2];
    const float* edge_val = (const float*)d_in[3];
    const float* w1       = (const float*)d_in[4];
    const float* b1       = (const float*)d_in[5];
    const float* w2       = (const float*)d_in[6];
    const float* b2       = (const float*)d_in[7];
    const float* wl       = (const float*)d_in[8];
    const float* bl       = (const float*)d_in[9];
    float* out = (float*)d_out;
    (void)in_sizes; (void)n_in; (void)out_size; (void)ws_size;

    // workspace layout (all buffers fully written before read, every call)
    char* ws = (char*)d_ws;
    size_t off = 0;
    int* row_ptr = (int*)(ws + off);
    off += (((size_t)(N_NODES + 1) * sizeof(int)) + 255) & ~(size_t)255;
    // x_cat[100000][192]: cols 0..63 <- x2 (layer2 out), cols 64..191 <- x1
    float* x_cat = (float*)(ws + off);   off += (size_t)N_NODES * 192 * sizeof(float);
    // support buffer: layer1 [100000][128]; reused layer2 [100000][64]; reused logits [100000][64]
    float* support = (float*)(ws + off); off += (size_t)N_NODES * NHID * sizeof(float);
    unsigned short* w1t = (unsigned short*)(ws + off); off += (size_t)NHID * NFEAT * sizeof(short);
    unsigned short* w2t = (unsigned short*)(ws + off); off += (size_t)NHID2 * NHID * sizeof(short);
    unsigned short* wlt = (unsigned short*)(ws + off); off += (size_t)NCLS_P * (NHID + NHID2) * sizeof(short);

    float* x1 = x_cat + NHID2;      // cols 64..191, stride 192
    float* x2 = x_cat;              // cols 0..63,   stride 192
    float* logits = support;        // reuse after spmm2 is done

    build_rowptr<<<(N_NODES + 1 + 255) / 256, 256, 0, stream>>>(edge_row, row_ptr, N_NODES, N_EDGES);
    conv_transpose_w<<<(NHID * NFEAT + 255) / 256, 256, 0, stream>>>(w1, w1t, NFEAT, NHID, NHID);
    conv_transpose_w<<<(NHID2 * NHID + 255) / 256, 256, 0, stream>>>(w2, w2t, NHID, NHID2, NHID2);
    conv_transpose_w<<<(NCLS_P * 192 + 255) / 256, 256, 0, stream>>>(wl, wlt, 192, NCLASS, NCLS_P);

    int mblocks = (N_NODES + 127) / 128;

    // layer 1: support = x @ w1 ; x1 = relu(spmm + b1)   (written into x_cat cols 64..191)
    gemm_bf16<NHID><<<dim3(mblocks, 1), 256, 0, stream>>>(x, w1t, support, N_NODES, NFEAT, NFEAT);
    spmm_bias_relu<NHID><<<(N_NODES + 3) / 4, 256, 0, stream>>>(
        support, row_ptr, edge_col, edge_val, b1, x1, 192, N_NODES);

    // layer 2: support2 = x1 @ w2 ; x2 = relu(spmm + b2)  (into x_cat cols 0..63)
    gemm_bf16<NHID2><<<dim3(mblocks, 1), 256, 0, stream>>>(x1, w2t, support, N_NODES, NHID, 192);
    spmm_bias_relu<NHID2><<<(N_NODES + 3) / 4, 256, 0, stream>>>(
        support, row_ptr, edge_col, edge_val, b2, x2, 192, N_NODES);

    // head: logits = x_cat @ wlt ; out = log_softmax(logits + bl)
    gemm_bf16<NCLS_P><<<dim3(mblocks, 1), 256, 0, stream>>>(x_cat, wlt, logits, N_NODES, NHID + NHID2, 192);
    logsm<<<(N_NODES + 3) / 4, 256, 0, stream>>>(logits, bl, out, N_NODES);
}

// Round 3
// 224.030 us; speedup vs baseline: 2.9782x; 1.8593x over previous
//
#include <hip/hip_runtime.h>
#include <math.h>

#define N_NODES 100000
#define N_EDGES 1600000
#define NFEAT   256
#define NHID    128
#define NHID2   64
#define NCLASS  40
#define NCLS_P  64

typedef __attribute__((ext_vector_type(8))) short bf16x8;
typedef __attribute__((ext_vector_type(4))) float f32x4;

static __device__ inline unsigned short f2bf(float f) {
    union { float f; unsigned u; } v; v.f = f;
    unsigned r = v.u + 0x7FFF + ((v.u >> 16) & 1);   // RNE
    return (unsigned short)(r >> 16);
}
static __device__ inline float bfl(unsigned u) {     // low bf16 -> f32
    union { unsigned u; float f; } v; v.u = u << 16; return v.f;
}
static __device__ inline float bfh(unsigned u) {     // high bf16 -> f32
    union { unsigned u; float f; } v; v.u = u & 0xffff0000u; return v.f;
}

// ---------------------------------------------------------------------------
// CSR row_ptr from sorted edge_row (lower_bound per node).
// ---------------------------------------------------------------------------
__global__ void build_rowptr(const int* __restrict__ edge_row,
                             int* __restrict__ row_ptr,
                             int n_nodes, int n_edges) {
    int n = blockIdx.x * blockDim.x + threadIdx.x;
    if (n > n_nodes) return;
    int lo = 0, hi = n_edges;
    while (lo < hi) {
        int mid = (lo + hi) >> 1;
        if (edge_row[mid] < n) lo = mid + 1; else hi = mid;
    }
    row_ptr[n] = lo;
}

// ---------------------------------------------------------------------------
// Weight prep: wt_bf16[NP][K] = transpose(w[K][N]), zero-pad rows n>=N.
// ---------------------------------------------------------------------------
__global__ void conv_transpose_w(const float* __restrict__ w,
                                 unsigned short* __restrict__ wt,
                                 int K, int N, int NP) {
    int idx = blockIdx.x * blockDim.x + threadIdx.x;
    if (idx >= NP * K) return;
    int n = idx / K, k = idx - n * K;
    float v = (n < N) ? w[(size_t)k * N + n] : 0.f;
    wt[(size_t)n * K + k] = f2bf(v);
}

// ---------------------------------------------------------------------------
// bf16 MFMA GEMM: C[M,BN] = A[M,K] @ Bt[BN,K]^T.  BM=128, BK=32, 4 waves.
// ABF16: A is bf16 (lda elems) else f32 (converted during staging).
// CBF16: C written as bf16 (stride BN) else f32.
// ---------------------------------------------------------------------------
template <int BN, int ABF16, int CBF16>
__global__ __launch_bounds__(256) void gemm_bf16(const void* __restrict__ A,
                                                 const unsigned short* __restrict__ Bt,
                                                 void* __restrict__ C,
                                                 int M, int K, int lda) {
    const int BKP = 40;                 // padded LDS row stride (bf16 elems)
    const int WN = BN / 2;              // wave n-extent (64 or 32)
    const int NF = WN / 16;             // n-frags per wave
    __shared__ unsigned short As[128 * BKP];
    __shared__ unsigned short Bs[BN * BKP];

    int tid = threadIdx.x;
    int lane = tid & 63, wid = tid >> 6;
    int wr = wid >> 1, wc = wid & 1;
    int row0 = blockIdx.x * 128;

    f32x4 acc[4][NF];
    #pragma unroll
    for (int i = 0; i < 4; ++i)
        #pragma unroll
        for (int j = 0; j < NF; ++j) acc[i][j] = f32x4{0.f, 0.f, 0.f, 0.f};

    for (int k0 = 0; k0 < K; k0 += 32) {
        if (ABF16) {
            const unsigned short* Ab = (const unsigned short*)A;
            #pragma unroll
            for (int i = 0; i < 2; ++i) {        // 512 slots of 8 bf16
                int s = tid + i * 256;
                int m = s >> 2, k = (s & 3) * 8;
                int row = row0 + m;
                uint4 a = (row < M) ? *(const uint4*)(Ab + (size_t)row * lda + k0 + k)
                                    : uint4{0u, 0u, 0u, 0u};
                *(uint4*)&As[m * BKP + k] = a;
            }
        } else {
            const float* Af = (const float*)A;
            #pragma unroll
            for (int i = 0; i < 4; ++i) {        // 1024 slots of 4 f32
                int s = tid + i * 256;
                int m = s >> 3, k = (s & 7) * 4;
                int row = row0 + m;
                float4 a = (row < M) ? *(const float4*)(Af + (size_t)row * lda + k0 + k)
                                     : float4{0.f, 0.f, 0.f, 0.f};
                ushort4 p; p.x = f2bf(a.x); p.y = f2bf(a.y); p.z = f2bf(a.z); p.w = f2bf(a.w);
                *(ushort4*)&As[m * BKP + k] = p;
            }
        }
        #pragma unroll
        for (int i = 0; i < (BN * 32) / (8 * 256); ++i) {
            int s = tid + i * 256;
            int n = s >> 2, k = (s & 3) * 8;
            *(uint4*)&Bs[n * BKP + k] = *(const uint4*)(Bt + (size_t)n * K + k0 + k);
        }
        __syncthreads();

        bf16x8 af[4], bfr[NF];
        #pragma unroll
        for (int mi = 0; mi < 4; ++mi)
            af[mi] = *(const bf16x8*)&As[(wr * 64 + mi * 16 + (lane & 15)) * BKP + (lane >> 4) * 8];
        #pragma unroll
        for (int ni = 0; ni < NF; ++ni)
            bfr[ni] = *(const bf16x8*)&Bs[(wc * WN + ni * 16 + (lane & 15)) * BKP + (lane >> 4) * 8];
        #pragma unroll
        for (int mi = 0; mi < 4; ++mi)
            #pragma unroll
            for (int ni = 0; ni < NF; ++ni)
                acc[mi][ni] = __builtin_amdgcn_mfma_f32_16x16x32_bf16(af[mi], bfr[ni], acc[mi][ni], 0, 0, 0);
        __syncthreads();
    }

    // epilogue: C/D layout col=lane&15, row=(lane>>4)*4+reg
    #pragma unroll
    for (int mi = 0; mi < 4; ++mi) {
        int rbase = row0 + wr * 64 + mi * 16 + ((lane >> 4) << 2);
        #pragma unroll
        for (int ni = 0; ni < NF; ++ni) {
            int col = wc * WN + ni * 16 + (lane & 15);
            #pragma unroll
            for (int r = 0; r < 4; ++r) {
                int row = rbase + r;
                if (row < M) {
                    if (CBF16) ((unsigned short*)C)[(size_t)row * BN + col] = f2bf(acc[mi][ni][r]);
                    else       ((float*)C)[(size_t)row * BN + col] = acc[mi][ni][r];
                }
            }
        }
    }
}

// ---------------------------------------------------------------------------
// SpMM (CSR, one wave per dst node) + bias + relu. sup/out are bf16, f32 acc.
// D=128: lane owns cols {2l,2l+1}, 4 edges in flight.
// D=64: half-wave per edge (256B gathers), shfl-combine, 2 pairs in flight.
// ---------------------------------------------------------------------------
template <int D>
__global__ __launch_bounds__(256) void spmm_bias_relu(const unsigned short* __restrict__ sup,
                                                      const int* __restrict__ row_ptr,
                                                      const int* __restrict__ edge_col,
                                                      const float* __restrict__ edge_val,
                                                      const float* __restrict__ bias,
                                                      unsigned short* __restrict__ out,
                                                      int out_stride, int n_nodes) {
    int wave = threadIdx.x >> 6;
    int lane = threadIdx.x & 63;
    int node = blockIdx.x * 4 + wave;
    if (node >= n_nodes) return;

    int e0 = row_ptr[node];
    int e1 = row_ptr[node + 1];
    const unsigned* supw = (const unsigned*)sup;     // ushort2 words

    if (D == 128) {
        float a0 = 0.f, a1 = 0.f, b0 = 0.f, b1 = 0.f;
        float c0 = 0.f, c1 = 0.f, d0 = 0.f, d1 = 0.f;
        int e = e0;
        for (; e + 3 < e1; e += 4) {
            int ca = edge_col[e],     cb = edge_col[e + 1];
            int cc = edge_col[e + 2], cd = edge_col[e + 3];
            float va = edge_val[e],     vb = edge_val[e + 1];
            float vc = edge_val[e + 2], vd = edge_val[e + 3];
            unsigned sa = supw[(size_t)ca * 64 + lane];
            unsigned sb = supw[(size_t)cb * 64 + lane];
            unsigned sc = supw[(size_t)cc * 64 + lane];
            unsigned sd = supw[(size_t)cd * 64 + lane];
            a0 += va * bfl(sa); a1 += va * bfh(sa);
            b0 += vb * bfl(sb); b1 += vb * bfh(sb);
            c0 += vc * bfl(sc); c1 += vc * bfh(sc);
            d0 += vd * bfl(sd); d1 += vd * bfh(sd);
        }
        for (; e < e1; ++e) {
            int c = edge_col[e]; float v = edge_val[e];
            unsigned s = supw[(size_t)c * 64 + lane];
            a0 += v * bfl(s); a1 += v * bfh(s);
        }
        float rx = (a0 + c0) + (b0 + d0) + bias[2 * lane];
        float ry = (a1 + c1) + (b1 + d1) + bias[2 * lane + 1];
        rx = rx > 0.f ? rx : 0.f; ry = ry > 0.f ? ry : 0.f;
        unsigned pk = (unsigned)f2bf(rx) | ((unsigned)f2bf(ry) << 16);
        ((unsigned*)(out + (size_t)node * out_stride))[lane] = pk;
    } else {
        int half = lane >> 5, l = lane & 31;
        float a0 = 0.f, a1 = 0.f, b0 = 0.f, b1 = 0.f;
        int e = e0;
        for (; e + 3 < e1; e += 4) {
            int ea = e + half, eb = e + 2 + half;
            int ca = edge_col[ea], cb = edge_col[eb];
            float va = edge_val[ea], vb = edge_val[eb];
            unsigned sa = supw[(size_t)ca * 32 + l];
            unsigned sb = supw[(size_t)cb * 32 + l];
            a0 += va * bfl(sa); a1 += va * bfh(sa);
            b0 += vb * bfl(sb); b1 += vb * bfh(sb);
        }
        for (; e < e1; e += 2) {
            int ee = e + half;
            bool ok = ee < e1;
            int c = ok ? edge_col[ee] : edge_col[e];
            float v = ok ? edge_val[ee] : 0.f;
            unsigned s = supw[(size_t)c * 32 + l];
            a0 += v * bfl(s); a1 += v * bfh(s);
        }
        a0 += b0; a1 += b1;
        a0 += __shfl_xor(a0, 32);
        a1 += __shfl_xor(a1, 32);
        if (half == 0) {
            float rx = a0 + bias[2 * l], ry = a1 + bias[2 * l + 1];
            rx = rx > 0.f ? rx : 0.f; ry = ry > 0.f ? ry : 0.f;
            unsigned pk = (unsigned)f2bf(rx) | ((unsigned)f2bf(ry) << 16);
            ((unsigned*)(out + (size_t)node * out_stride))[l] = pk;
        }
    }
}

// ---------------------------------------------------------------------------
// Fused head: out = log_softmax(x_cat[M,192](bf16) @ wlt[64,192]^T + bl).
// Same MFMA structure (BM=128, BN=64); logits staged to LDS, softmax per row.
// ---------------------------------------------------------------------------
__global__ __launch_bounds__(256) void head_fused(const unsigned short* __restrict__ A,
                                                  const unsigned short* __restrict__ Bt,
                                                  const float* __restrict__ bl,
                                                  float* __restrict__ out, int M) {
    const int BKP = 40;
    __shared__ unsigned short As[128 * BKP];
    __shared__ unsigned short Bs[64 * BKP];
    __shared__ float L[128][65];
    __shared__ float bls[NCLASS];

    int tid = threadIdx.x;
    int lane = tid & 63, wid = tid >> 6;
    int wr = wid >> 1, wc = wid & 1;
    int row0 = blockIdx.x * 128;
    if (tid < NCLASS) bls[tid] = bl[tid];

    f32x4 acc[4][2];
    #pragma unroll
    for (int i = 0; i < 4; ++i)
        #pragma unroll
        for (int j = 0; j < 2; ++j) acc[i][j] = f32x4{0.f, 0.f, 0.f, 0.f};

    for (int k0 = 0; k0 < 192; k0 += 32) {
        #pragma unroll
        for (int i = 0; i < 2; ++i) {
            int s = tid + i * 256;
            int m = s >> 2, k = (s & 3) * 8;
            int row = row0 + m;
            uint4 a = (row < M) ? *(const uint4*)(A + (size_t)row * 192 + k0 + k)
                                : uint4{0u, 0u, 0u, 0u};
            *(uint4*)&As[m * BKP + k] = a;
        }
        {
            int n = tid >> 2, k = (tid & 3) * 8;
            *(uint4*)&Bs[n * BKP + k] = *(const uint4*)(Bt + (size_t)n * 192 + k0 + k);
        }
        __syncthreads();

        bf16x8 af[4], bfr[2];
        #pragma unroll
        for (int mi = 0; mi < 4; ++mi)
            af[mi] = *(const bf16x8*)&As[(wr * 64 + mi * 16 + (lane & 15)) * BKP + (lane >> 4) * 8];
        #pragma unroll
        for (int ni = 0; ni < 2; ++ni)
            bfr[ni] = *(const bf16x8*)&Bs[(wc * 32 + ni * 16 + (lane & 15)) * BKP + (lane >> 4) * 8];
        #pragma unroll
        for (int mi = 0; mi < 4; ++mi)
            #pragma unroll
            for (int ni = 0; ni < 2; ++ni)
                acc[mi][ni] = __builtin_amdgcn_mfma_f32_16x16x32_bf16(af[mi], bfr[ni], acc[mi][ni], 0, 0, 0);
        __syncthreads();
    }

    // stage logits to LDS
    #pragma unroll
    for (int mi = 0; mi < 4; ++mi) {
        int rt = wr * 64 + mi * 16 + ((lane >> 4) << 2);
        #pragma unroll
        for (int ni = 0; ni < 2; ++ni) {
            int ct = wc * 32 + ni * 16 + (lane & 15);
            #pragma unroll
            for (int r = 0; r < 4; ++r) L[rt + r][ct] = acc[mi][ni][r];
        }
    }
    __syncthreads();

    if (tid < 128) {
        int row = row0 + tid;
        if (row < M) {
            float m = -1e30f;
            #pragma unroll 8
            for (int c = 0; c < NCLASS; ++c) {
                float t = L[tid][c] + bls[c];
                L[tid][c] = t;
                m = fmaxf(m, t);
            }
            float s = 0.f;
            #pragma unroll 8
            for (int c = 0; c < NCLASS; ++c) s += __expf(L[tid][c] - m);
            float lg = __logf(s);
            float* o = out + (size_t)row * NCLASS;
            #pragma unroll 8
            for (int c = 0; c < NCLASS; ++c) o[c] = L[tid][c] - m - lg;
        }
    }
}

// ---------------------------------------------------------------------------
extern "C" void kernel_launch(void* const* d_in, const int* in_sizes, int n_in,
                              void* d_out, int out_size, void* d_ws, size_t ws_size,
                              hipStream_t stream) {
    const float* x        = (const float*)d_in[0];
    const int*   edge_row = (const int*)d_in[1];
    const int*   edge_col = (const int*)d_in[2];
    const float* edge_val = (const float*)d_in[3];
    const float* w1       = (const float*)d_in[4];
    const float* b1       = (const float*)d_in[5];
    const float* w2       = (const float*)d_in[6];
    const float* b2       = (const float*)d_in[7];
    const float* wl       = (const float*)d_in[8];
    const float* bl       = (const float*)d_in[9];
    float* out = (float*)d_out;
    (void)in_sizes; (void)n_in; (void)out_size; (void)ws_size;

    char* ws = (char*)d_ws;
    size_t off = 0;
    int* row_ptr = (int*)(ws + off);
    off += (((size_t)(N_NODES + 1) * sizeof(int)) + 255) & ~(size_t)255;
    // x_cat bf16 [N][192]: cols 0..63 <- x2, cols 64..191 <- x1
    unsigned short* x_cat = (unsigned short*)(ws + off);
    off += (size_t)N_NODES * 192 * sizeof(short);
    // support bf16: layer1 [N][128]; reused as layer2 [N][64]
    unsigned short* sup = (unsigned short*)(ws + off);
    off += (size_t)N_NODES * NHID * sizeof(short);
    unsigned short* w1t = (unsigned short*)(ws + off); off += (size_t)NHID * NFEAT * sizeof(short);
    unsigned short* w2t = (unsigned short*)(ws + off); off += (size_t)NHID2 * NHID * sizeof(short);
    unsigned short* wlt = (unsigned short*)(ws + off); off += (size_t)NCLS_P * 192 * sizeof(short);

    unsigned short* x1 = x_cat + NHID2;   // cols 64..191, stride 192
    unsigned short* x2 = x_cat;           // cols 0..63,   stride 192

    build_rowptr<<<(N_NODES + 1 + 255) / 256, 256, 0, stream>>>(edge_row, row_ptr, N_NODES, N_EDGES);
    conv_transpose_w<<<(NHID * NFEAT + 255) / 256, 256, 0, stream>>>(w1, w1t, NFEAT, NHID, NHID);
    conv_transpose_w<<<(NHID2 * NHID + 255) / 256, 256, 0, stream>>>(w2, w2t, NHID, NHID2, NHID2);
    conv_transpose_w<<<(NCLS_P * 192 + 255) / 256, 256, 0, stream>>>(wl, wlt, 192, NCLASS, NCLS_P);

    int mblocks = (N_NODES + 127) / 128;

    // layer 1
    gemm_bf16<NHID, 0, 1><<<dim3(mblocks, 1), 256, 0, stream>>>(x, w1t, sup, N_NODES, NFEAT, NFEAT);
    spmm_bias_relu<NHID><<<(N_NODES + 3) / 4, 256, 0, stream>>>(
        sup, row_ptr, edge_col, edge_val, b1, x1, 192, N_NODES);

    // layer 2
    gemm_bf16<NHID2, 1, 1><<<dim3(mblocks, 1), 256, 0, stream>>>(x1, w2t, sup, N_NODES, NHID, 192);
    spmm_bias_relu<NHID2><<<(N_NODES + 3) / 4, 256, 0, stream>>>(
        sup, row_ptr, edge_col, edge_val, b2, x2, 192, N_NODES);

    // fused head
    head_fused<<<dim3(mblocks, 1), 256, 0, stream>>>(x_cat, wlt, bl, out, N_NODES);
}

// Round 6
// 191.686 us; speedup vs baseline: 3.4807x; 1.1687x over previous
//
#include <hip/hip_runtime.h>
#include <math.h>

#define N_NODES 100000
#define N_EDGES 1600000
#define NFEAT   256
#define NHID    128
#define NHID2   64
#define NCLASS  40
#define NCLS_P  64

typedef __attribute__((ext_vector_type(8))) short bf16x8;
typedef __attribute__((ext_vector_type(4))) float f32x4;

static __device__ inline unsigned short f2bf(float f) {
    union { float f; unsigned u; } v; v.f = f;
    unsigned r = v.u + 0x7FFF + ((v.u >> 16) & 1);   // RNE
    return (unsigned short)(r >> 16);
}
static __device__ inline unsigned pkbf(float a, float b) {   // packed bf16x2
    return (unsigned)f2bf(a) | ((unsigned)f2bf(b) << 16);
}
static __device__ inline float bfl(unsigned u) {
    union { unsigned u; float f; } v; v.u = u << 16; return v.f;
}
static __device__ inline float bfh(unsigned u) {
    union { unsigned u; float f; } v; v.u = u & 0xffff0000u; return v.f;
}

// ---------------------------------------------------------------------------
// Merged prep: CSR row_ptr (lower_bound) + 3 weight transpose/bf16 converts.
// Flat-index ranges are disjoint.
// ---------------------------------------------------------------------------
#define PREP_T0 (N_NODES + 1)
#define PREP_T1 (PREP_T0 + NHID * NFEAT)
#define PREP_T2 (PREP_T1 + NHID2 * NHID)
#define PREP_T3 (PREP_T2 + NCLS_P * 192)
__global__ void prep(const int* __restrict__ er, int* __restrict__ row_ptr,
                     const float* __restrict__ w1, unsigned short* __restrict__ w1t,
                     const float* __restrict__ w2, unsigned short* __restrict__ w2t,
                     const float* __restrict__ wl, unsigned short* __restrict__ wlt) {
    int idx = blockIdx.x * blockDim.x + threadIdx.x;
    if (idx < PREP_T0) {
        int lo = 0, hi = N_EDGES;
        while (lo < hi) { int mid = (lo + hi) >> 1; if (er[mid] < idx) lo = mid + 1; else hi = mid; }
        row_ptr[idx] = lo;
    } else if (idx < PREP_T1) {
        int i = idx - PREP_T0;          // w1t[n][k]: n<128, k<256
        int n = i >> 8, k = i & 255;
        w1t[i] = f2bf(w1[k * NHID + n]);
    } else if (idx < PREP_T2) {
        int i = idx - PREP_T1;          // w2t[n][k]: n<64, k<128
        int n = i >> 7, k = i & 127;
        w2t[i] = f2bf(w2[k * NHID2 + n]);
    } else if (idx < PREP_T3) {
        int i = idx - PREP_T2;          // wlt[n][k]: n<64 (pad>=40 -> 0), k<192
        int n = i / 192, k = i - n * 192;
        wlt[i] = (n < NCLASS) ? f2bf(wl[k * NCLASS + n]) : (unsigned short)0;
    }
}

// ---------------------------------------------------------------------------
// bf16 MFMA GEMM: C[M,BN] = A[M,K] @ Bt[BN,K]^T.  BM=128, BK=32, 4 waves.
// ---------------------------------------------------------------------------
template <int BN, int ABF16, int CBF16>
__global__ __launch_bounds__(256) void gemm_bf16(const void* __restrict__ A,
                                                 const unsigned short* __restrict__ Bt,
                                                 void* __restrict__ C,
                                                 int M, int K, int lda) {
    const int BKP = 40;
    const int WN = BN / 2;
    const int NF = WN / 16;
    __shared__ unsigned short As[128 * BKP];
    __shared__ unsigned short Bs[BN * BKP];

    int tid = threadIdx.x;
    int lane = tid & 63, wid = tid >> 6;
    int wr = wid >> 1, wc = wid & 1;
    int row0 = blockIdx.x * 128;

    f32x4 acc[4][NF];
    #pragma unroll
    for (int i = 0; i < 4; ++i)
        #pragma unroll
        for (int j = 0; j < NF; ++j) acc[i][j] = f32x4{0.f, 0.f, 0.f, 0.f};

    for (int k0 = 0; k0 < K; k0 += 32) {
        if (ABF16) {
            const unsigned short* Ab = (const unsigned short*)A;
            #pragma unroll
            for (int i = 0; i < 2; ++i) {
                int s = tid + i * 256;
                int m = s >> 2, k = (s & 3) * 8;
                int row = row0 + m;
                uint4 a = (row < M) ? *(const uint4*)(Ab + (size_t)row * lda + k0 + k)
                                    : uint4{0u, 0u, 0u, 0u};
                *(uint4*)&As[m * BKP + k] = a;
            }
        } else {
            const float* Af = (const float*)A;
            #pragma unroll
            for (int i = 0; i < 4; ++i) {
                int s = tid + i * 256;
                int m = s >> 3, k = (s & 7) * 4;
                int row = row0 + m;
                float4 a = (row < M) ? *(const float4*)(Af + (size_t)row * lda + k0 + k)
                                     : float4{0.f, 0.f, 0.f, 0.f};
                uint2 p; p.x = pkbf(a.x, a.y); p.y = pkbf(a.z, a.w);
                *(uint2*)&As[m * BKP + k] = p;
            }
        }
        #pragma unroll
        for (int i = 0; i < (BN * 32) / (8 * 256); ++i) {
            int s = tid + i * 256;
            int n = s >> 2, k = (s & 3) * 8;
            *(uint4*)&Bs[n * BKP + k] = *(const uint4*)(Bt + (size_t)n * K + k0 + k);
        }
        __syncthreads();

        bf16x8 af[4], bfr[NF];
        #pragma unroll
        for (int mi = 0; mi < 4; ++mi)
            af[mi] = *(const bf16x8*)&As[(wr * 64 + mi * 16 + (lane & 15)) * BKP + (lane >> 4) * 8];
        #pragma unroll
        for (int ni = 0; ni < NF; ++ni)
            bfr[ni] = *(const bf16x8*)&Bs[(wc * WN + ni * 16 + (lane & 15)) * BKP + (lane >> 4) * 8];
        #pragma unroll
        for (int mi = 0; mi < 4; ++mi)
            #pragma unroll
            for (int ni = 0; ni < NF; ++ni)
                acc[mi][ni] = __builtin_amdgcn_mfma_f32_16x16x32_bf16(af[mi], bfr[ni], acc[mi][ni], 0, 0, 0);
        __syncthreads();
    }

    #pragma unroll
    for (int mi = 0; mi < 4; ++mi) {
        int rbase = row0 + wr * 64 + mi * 16 + ((lane >> 4) << 2);
        #pragma unroll
        for (int ni = 0; ni < NF; ++ni) {
            int col = wc * WN + ni * 16 + (lane & 15);
            #pragma unroll
            for (int r = 0; r < 4; ++r) {
                int row = rbase + r;
                if (row < M) {
                    if (CBF16) ((unsigned short*)C)[(size_t)row * BN + col] = f2bf(acc[mi][ni][r]);
                    else       ((float*)C)[(size_t)row * BN + col] = acc[mi][ni][r];
                }
            }
        }
    }
}

// ---------------------------------------------------------------------------
// SpMM (CSR, one wave per dst node) + bias + relu. bf16 storage, f32 acc.
// Metadata: coalesced lane-per-edge preload + readlane broadcast (SGPR cols ->
// scalar addresses, no per-lane address math, 1 vmem per gather).
// D=128: 8 gathers (256B each) in flight. D=64: 4 two-edge gathers in flight.
// OOB tail lanes clamp to row 0 with v=0 (row 0 stays L1-hot, adds 0).
// ---------------------------------------------------------------------------
template <int D>
__global__ __launch_bounds__(256) void spmm_bias_relu(const unsigned short* __restrict__ sup,
                                                      const int* __restrict__ row_ptr,
                                                      const int* __restrict__ edge_col,
                                                      const float* __restrict__ edge_val,
                                                      const float* __restrict__ bias,
                                                      unsigned short* __restrict__ out,
                                                      int out_stride, int n_nodes) {
    int wave = threadIdx.x >> 6;
    int lane = threadIdx.x & 63;
    int node = blockIdx.x * 4 + wave;
    if (node >= n_nodes) return;

    int e0 = row_ptr[node];
    int cnt = row_ptr[node + 1] - e0;
    const char* base = (const char*)sup;

    float ax[4] = {0.f, 0.f, 0.f, 0.f}, ay[4] = {0.f, 0.f, 0.f, 0.f};

    for (int o = 0; o < cnt; o += 64) {
        int rem = min(64, cnt - o);
        int mc = 0; float mv = 0.f;
        if (lane < rem) {
            mc = edge_col[e0 + o + lane];
            mv = edge_val[e0 + o + lane];
        }
        int mvb = __builtin_bit_cast(int, mv);

        if (D == 128) {
            for (int j = 0; j < rem; j += 8) {
                unsigned g[8]; float v[8];
                #pragma unroll
                for (int t = 0; t < 8; ++t) {
                    int jt = j + t;
                    int c  = __builtin_amdgcn_readlane(mc, jt);
                    int vb = __builtin_amdgcn_readlane(mvb, jt);
                    bool ok = jt < rem;                 // wave-uniform
                    c    = ok ? c : 0;
                    v[t] = ok ? __builtin_bit_cast(float, vb) : 0.f;
                    g[t] = *(const unsigned*)(base + (((unsigned)c) << 8) + (lane << 2));
                }
                #pragma unroll
                for (int t = 0; t < 8; ++t) {
                    ax[t & 3] += v[t] * bfl(g[t]);
                    ay[t & 3] += v[t] * bfh(g[t]);
                }
            }
        } else {
            int hf = lane >> 5, l = lane & 31;
            for (int j = 0; j < rem; j += 8) {
                unsigned g[4]; float v[4];
                #pragma unroll
                for (int t = 0; t < 4; ++t) {
                    int j0 = j + 2 * t, j1 = j0 + 1;
                    int c0 = __builtin_amdgcn_readlane(mc, j0);
                    int c1 = __builtin_amdgcn_readlane(mc, j1);
                    int w0 = __builtin_amdgcn_readlane(mvb, j0);
                    int w1 = __builtin_amdgcn_readlane(mvb, j1);
                    c0 = (j0 < rem) ? c0 : 0;
                    c1 = (j1 < rem) ? c1 : 0;
                    float f0 = (j0 < rem) ? __builtin_bit_cast(float, w0) : 0.f;
                    float f1 = (j1 < rem) ? __builtin_bit_cast(float, w1) : 0.f;
                    int c = hf ? c1 : c0;
                    v[t]  = hf ? f1 : f0;
                    g[t] = *(const unsigned*)(base + (((unsigned)c) << 7) + (l << 2));
                }
                #pragma unroll
                for (int t = 0; t < 4; ++t) {
                    ax[t] += v[t] * bfl(g[t]);
                    ay[t] += v[t] * bfh(g[t]);
                }
            }
        }
    }

    float sx = (ax[0] + ax[1]) + (ax[2] + ax[3]);
    float sy = (ay[0] + ay[1]) + (ay[2] + ay[3]);
    if (D == 64) {
        sx += __shfl_xor(sx, 32);
        sy += __shfl_xor(sy, 32);
    }
    int l = (D == 128) ? lane : (lane & 31);
    if (D == 128 || lane < 32) {
        float rx = sx + bias[2 * l], ry = sy + bias[2 * l + 1];
        rx = rx > 0.f ? rx : 0.f; ry = ry > 0.f ? ry : 0.f;
        ((unsigned*)(out + (size_t)node * out_stride))[l] = pkbf(rx, ry);
    }
}

// ---------------------------------------------------------------------------
// Fused head: out = log_softmax(x_cat[M,192](bf16) @ wlt[64,192]^T + bl).
// ---------------------------------------------------------------------------
__global__ __launch_bounds__(256) void head_fused(const unsigned short* __restrict__ A,
                                                  const unsigned short* __restrict__ Bt,
                                                  const float* __restrict__ bl,
                                                  float* __restrict__ out, int M) {
    const int BKP = 40;
    __shared__ unsigned short As[128 * BKP];
    __shared__ unsigned short Bs[64 * BKP];
    __shared__ float L[128][65];
    __shared__ float bls[NCLASS];

    int tid = threadIdx.x;
    int lane = tid & 63, wid = tid >> 6;
    int wr = wid >> 1, wc = wid & 1;
    int row0 = blockIdx.x * 128;
    if (tid < NCLASS) bls[tid] = bl[tid];

    f32x4 acc[4][2];
    #pragma unroll
    for (int i = 0; i < 4; ++i)
        #pragma unroll
        for (int j = 0; j < 2; ++j) acc[i][j] = f32x4{0.f, 0.f, 0.f, 0.f};

    for (int k0 = 0; k0 < 192; k0 += 32) {
        #pragma unroll
        for (int i = 0; i < 2; ++i) {
            int s = tid + i * 256;
            int m = s >> 2, k = (s & 3) * 8;
            int row = row0 + m;
            uint4 a = (row < M) ? *(const uint4*)(A + (size_t)row * 192 + k0 + k)
                                : uint4{0u, 0u, 0u, 0u};
            *(uint4*)&As[m * BKP + k] = a;
        }
        {
            int n = tid >> 2, k = (tid & 3) * 8;
            *(uint4*)&Bs[n * BKP + k] = *(const uint4*)(Bt + (size_t)n * 192 + k0 + k);
        }
        __syncthreads();

        bf16x8 af[4], bfr[2];
        #pragma unroll
        for (int mi = 0; mi < 4; ++mi)
            af[mi] = *(const bf16x8*)&As[(wr * 64 + mi * 16 + (lane & 15)) * BKP + (lane >> 4) * 8];
        #pragma unroll
        for (int ni = 0; ni < 2; ++ni)
            bfr[ni] = *(const bf16x8*)&Bs[(wc * 32 + ni * 16 + (lane & 15)) * BKP + (lane >> 4) * 8];
        #pragma unroll
        for (int mi = 0; mi < 4; ++mi)
            #pragma unroll
            for (int ni = 0; ni < 2; ++ni)
                acc[mi][ni] = __builtin_amdgcn_mfma_f32_16x16x32_bf16(af[mi], bfr[ni], acc[mi][ni], 0, 0, 0);
        __syncthreads();
    }

    #pragma unroll
    for (int mi = 0; mi < 4; ++mi) {
        int rt = wr * 64 + mi * 16 + ((lane >> 4) << 2);
        #pragma unroll
        for (int ni = 0; ni < 2; ++ni) {
            int ct = wc * 32 + ni * 16 + (lane & 15);
            #pragma unroll
            for (int r = 0; r < 4; ++r) L[rt + r][ct] = acc[mi][ni][r];
        }
    }
    __syncthreads();

    // softmax: 2 threads per row (20 classes each), shfl_xor(1) combine
    {
        int r = tid >> 1, h = tid & 1;
        int row = row0 + r;
        if (row < M) {
            float m = -1e30f;
            #pragma unroll
            for (int c = 0; c < 20; ++c) {
                float t = L[r][h * 20 + c] + bls[h * 20 + c];
                L[r][h * 20 + c] = t;
                m = fmaxf(m, t);
            }
            m = fmaxf(m, __shfl_xor(m, 1));
            float s = 0.f;
            #pragma unroll
            for (int c = 0; c < 20; ++c) s += __expf(L[r][h * 20 + c] - m);
            s += __shfl_xor(s, 1);
            float lg = __logf(s);
            float* o = out + (size_t)row * NCLASS + h * 20;
            #pragma unroll
            for (int c = 0; c < 20; ++c) o[c] = L[r][h * 20 + c] - m - lg;
        }
    }
}

// ---------------------------------------------------------------------------
extern "C" void kernel_launch(void* const* d_in, const int* in_sizes, int n_in,
                              void* d_out, int out_size, void* d_ws, size_t ws_size,
                              hipStream_t stream) {
    const float* x        = (const float*)d_in[0];
    const int*   edge_row = (const int*)d_in[1];
    const int*   edge_col = (const int*)d_in[2];
    const float* edge_val = (const float*)d_in[3];
    const float* w1       = (const float*)d_in[4];
    const float* b1       = (const float*)d_in[5];
    const float* w2       = (const float*)d_in[6];
    const float* b2       = (const float*)d_in[7];
    const float* wl       = (const float*)d_in[8];
    const float* bl       = (const float*)d_in[9];
    float* out = (float*)d_out;
    (void)in_sizes; (void)n_in; (void)out_size; (void)ws_size;

    char* ws = (char*)d_ws;
    size_t off = 0;
    int* row_ptr = (int*)(ws + off);
    off += (((size_t)(N_NODES + 1) * sizeof(int)) + 255) & ~(size_t)255;
    unsigned short* x_cat = (unsigned short*)(ws + off);
    off += (size_t)N_NODES * 192 * sizeof(short);
    unsigned short* sup = (unsigned short*)(ws + off);
    off += (size_t)N_NODES * NHID * sizeof(short);
    unsigned short* w1t = (unsigned short*)(ws + off); off += (size_t)NHID * NFEAT * sizeof(short);
    unsigned short* w2t = (unsigned short*)(ws + off); off += (size_t)NHID2 * NHID * sizeof(short);
    unsigned short* wlt = (unsigned short*)(ws + off); off += (size_t)NCLS_P * 192 * sizeof(short);

    unsigned short* x1 = x_cat + NHID2;   // cols 64..191, stride 192
    unsigned short* x2 = x_cat;           // cols 0..63,   stride 192

    prep<<<(PREP_T3 + 255) / 256, 256, 0, stream>>>(edge_row, row_ptr, w1, w1t, w2, w2t, wl, wlt);

    int mblocks = (N_NODES + 127) / 128;

    // layer 1
    gemm_bf16<NHID, 0, 1><<<dim3(mblocks, 1), 256, 0, stream>>>(x, w1t, sup, N_NODES, NFEAT, NFEAT);
    spmm_bias_relu<NHID><<<(N_NODES + 3) / 4, 256, 0, stream>>>(
        sup, row_ptr, edge_col, edge_val, b1, x1, 192, N_NODES);

    // layer 2
    gemm_bf16<NHID2, 1, 1><<<dim3(mblocks, 1), 256, 0, stream>>>(x1, w2t, sup, N_NODES, NHID, 192);
    spmm_bias_relu<NHID2><<<(N_NODES + 3) / 4, 256, 0, stream>>>(
        sup, row_ptr, edge_col, edge_val, b2, x2, 192, N_NODES);

    // fused head
    head_fused<<<dim3(mblocks, 1), 256, 0, stream>>>(x_cat, wlt, bl, out, N_NODES);
}

// Round 7
// 177.386 us; speedup vs baseline: 3.7613x; 1.0806x over previous
//
#include <hip/hip_runtime.h>
#include <math.h>

#define N_NODES 100000
#define N_EDGES 1600000
#define NFEAT   256
#define NHID    128
#define NHID2   64
#define NCLASS  40
#define NCLS_P  64

typedef __attribute__((ext_vector_type(8))) short bf16x8;
typedef __attribute__((ext_vector_type(4))) float f32x4;

static __device__ inline unsigned short f2bf(float f) {
    union { float f; unsigned u; } v; v.f = f;
    unsigned r = v.u + 0x7FFF + ((v.u >> 16) & 1);   // RNE
    return (unsigned short)(r >> 16);
}
static __device__ inline unsigned pkbf(float a, float b) {   // packed bf16x2
    return (unsigned)f2bf(a) | ((unsigned)f2bf(b) << 16);
}
static __device__ inline float bfl(unsigned u) {
    union { unsigned u; float f; } v; v.u = u << 16; return v.f;
}
static __device__ inline float bfh(unsigned u) {
    union { unsigned u; float f; } v; v.u = u & 0xffff0000u; return v.f;
}

// ---------------------------------------------------------------------------
// Merged prep: CSR row_ptr (lower_bound) + 3 weight transpose/bf16 converts.
// ---------------------------------------------------------------------------
#define PREP_T0 (N_NODES + 1)
#define PREP_T1 (PREP_T0 + NHID * NFEAT)
#define PREP_T2 (PREP_T1 + NHID2 * NHID)
#define PREP_T3 (PREP_T2 + NCLS_P * 192)
__global__ void prep(const int* __restrict__ er, int* __restrict__ row_ptr,
                     const float* __restrict__ w1, unsigned short* __restrict__ w1t,
                     const float* __restrict__ w2, unsigned short* __restrict__ w2t,
                     const float* __restrict__ wl, unsigned short* __restrict__ wlt) {
    int idx = blockIdx.x * blockDim.x + threadIdx.x;
    if (idx < PREP_T0) {
        int lo = 0, hi = N_EDGES;
        while (lo < hi) { int mid = (lo + hi) >> 1; if (er[mid] < idx) lo = mid + 1; else hi = mid; }
        row_ptr[idx] = lo;
    } else if (idx < PREP_T1) {
        int i = idx - PREP_T0;          // w1t[n][k]: n<128, k<256
        int n = i >> 8, k = i & 255;
        w1t[i] = f2bf(w1[k * NHID + n]);
    } else if (idx < PREP_T2) {
        int i = idx - PREP_T1;          // w2t[n][k]: n<64, k<128
        int n = i >> 7, k = i & 127;
        w2t[i] = f2bf(w2[k * NHID2 + n]);
    } else if (idx < PREP_T3) {
        int i = idx - PREP_T2;          // wlt[n][k]: n<64 (pad>=40 -> 0), k<192
        int n = i / 192, k = i - n * 192;
        wlt[i] = (n < NCLASS) ? f2bf(wl[k * NCLASS + n]) : (unsigned short)0;
    }
}

// ---------------------------------------------------------------------------
// bf16 MFMA GEMM: C[M,BN] = A[M,K] @ Bt[BN,K]^T.
// BM=128, BK=32, 512 threads (8 waves). Reg-staged double-buffered LDS:
// loads for tile t+1 issue before compute(t); one barrier per K-step.
// BN=128: wave tile 64x32 (MF=4,NF=2). BN=64: 32x32 (MF=2,NF=2).
// ---------------------------------------------------------------------------
template <int BN, int ABF16, int CBF16>
__global__ __launch_bounds__(512) void gemm_bf16(const void* __restrict__ A,
                                                 const unsigned short* __restrict__ Bt,
                                                 void* __restrict__ C,
                                                 int M, int K, int lda) {
    const int BKP = 40;
    const int WC = (BN == 128) ? 4 : 2;
    const int WR = 8 / WC;
    const int MF = (128 / WR) / 16;      // 4 (BN=128) or 2 (BN=64)
    const int NF = (BN / WC) / 16;       // 2
    __shared__ unsigned short As[2][128 * BKP];
    __shared__ unsigned short Bs[2][BN * BKP];

    int tid = threadIdx.x;
    int lane = tid & 63, wid = tid >> 6;
    int wr = wid / WC, wc = wid % WC;
    int row0 = blockIdx.x * 128;

    f32x4 acc[MF][NF];
    #pragma unroll
    for (int i = 0; i < MF; ++i)
        #pragma unroll
        for (int j = 0; j < NF; ++j) acc[i][j] = f32x4{0.f, 0.f, 0.f, 0.f};

    float4 arf[2]; uint4 arb; uint4 brg;

    auto LOAD = [&](int t) {
        int k0 = t * 32;
        if (ABF16) {
            const unsigned short* Ab = (const unsigned short*)A;
            int m = tid >> 2, k = (tid & 3) * 8;
            int row = row0 + m;
            arb = (row < M) ? *(const uint4*)(Ab + (size_t)row * lda + k0 + k)
                            : uint4{0u, 0u, 0u, 0u};
        } else {
            const float* Af = (const float*)A;
            #pragma unroll
            for (int i = 0; i < 2; ++i) {
                int s = tid + i * 512;
                int m = s >> 3, k = (s & 7) * 4;
                int row = row0 + m;
                arf[i] = (row < M) ? *(const float4*)(Af + (size_t)row * lda + k0 + k)
                                   : float4{0.f, 0.f, 0.f, 0.f};
            }
        }
        if (BN == 128 || tid < 256) {
            int n = tid >> 2, k = (tid & 3) * 8;
            brg = *(const uint4*)(Bt + (size_t)n * K + k0 + k);
        }
    };
    auto STORE = [&](int b) {
        if (ABF16) {
            int m = tid >> 2, k = (tid & 3) * 8;
            *(uint4*)&As[b][m * BKP + k] = arb;
        } else {
            #pragma unroll
            for (int i = 0; i < 2; ++i) {
                int s = tid + i * 512;
                int m = s >> 3, k = (s & 7) * 4;
                uint2 p; p.x = pkbf(arf[i].x, arf[i].y); p.y = pkbf(arf[i].z, arf[i].w);
                *(uint2*)&As[b][m * BKP + k] = p;
            }
        }
        if (BN == 128 || tid < 256) {
            int n = tid >> 2, k = (tid & 3) * 8;
            *(uint4*)&Bs[b][n * BKP + k] = brg;
        }
    };

    const int NT = K / 32;
    LOAD(0); STORE(0);
    __syncthreads();
    for (int t = 0; t < NT; ++t) {
        int cur = t & 1;
        if (t + 1 < NT) LOAD(t + 1);       // in flight during compute
        bf16x8 af[MF], bfr[NF];
        #pragma unroll
        for (int mi = 0; mi < MF; ++mi)
            af[mi] = *(const bf16x8*)&As[cur][(wr * (MF * 16) + mi * 16 + (lane & 15)) * BKP + (lane >> 4) * 8];
        #pragma unroll
        for (int ni = 0; ni < NF; ++ni)
            bfr[ni] = *(const bf16x8*)&Bs[cur][(wc * (NF * 16) + ni * 16 + (lane & 15)) * BKP + (lane >> 4) * 8];
        #pragma unroll
        for (int mi = 0; mi < MF; ++mi)
            #pragma unroll
            for (int ni = 0; ni < NF; ++ni)
                acc[mi][ni] = __builtin_amdgcn_mfma_f32_16x16x32_bf16(af[mi], bfr[ni], acc[mi][ni], 0, 0, 0);
        if (t + 1 < NT) {
            STORE(cur ^ 1);
            __syncthreads();
        }
    }

    #pragma unroll
    for (int mi = 0; mi < MF; ++mi) {
        int rbase = row0 + wr * (MF * 16) + mi * 16 + ((lane >> 4) << 2);
        #pragma unroll
        for (int ni = 0; ni < NF; ++ni) {
            int col = wc * (NF * 16) + ni * 16 + (lane & 15);
            #pragma unroll
            for (int r = 0; r < 4; ++r) {
                int row = rbase + r;
                if (row < M) {
                    if (CBF16) ((unsigned short*)C)[(size_t)row * BN + col] = f2bf(acc[mi][ni][r]);
                    else       ((float*)C)[(size_t)row * BN + col] = acc[mi][ni][r];
                }
            }
        }
    }
}

// ---------------------------------------------------------------------------
// SpMM (CSR, one wave per dst node) + bias + relu. bf16 storage, f32 acc.
// readlane-broadcast metadata; 8 (D=128) / 4x2 (D=64) gathers in flight.
// ---------------------------------------------------------------------------
template <int D>
__global__ __launch_bounds__(256) void spmm_bias_relu(const unsigned short* __restrict__ sup,
                                                      const int* __restrict__ row_ptr,
                                                      const int* __restrict__ edge_col,
                                                      const float* __restrict__ edge_val,
                                                      const float* __restrict__ bias,
                                                      unsigned short* __restrict__ out,
                                                      int out_stride, int n_nodes) {
    int wave = threadIdx.x >> 6;
    int lane = threadIdx.x & 63;
    int node = blockIdx.x * 4 + wave;
    if (node >= n_nodes) return;

    int e0 = row_ptr[node];
    int cnt = row_ptr[node + 1] - e0;
    const char* base = (const char*)sup;

    float ax[4] = {0.f, 0.f, 0.f, 0.f}, ay[4] = {0.f, 0.f, 0.f, 0.f};

    for (int o = 0; o < cnt; o += 64) {
        int rem = min(64, cnt - o);
        int mc = 0; float mv = 0.f;
        if (lane < rem) {
            mc = edge_col[e0 + o + lane];
            mv = edge_val[e0 + o + lane];
        }
        int mvb = __builtin_bit_cast(int, mv);

        if (D == 128) {
            for (int j = 0; j < rem; j += 8) {
                unsigned g[8]; float v[8];
                #pragma unroll
                for (int t = 0; t < 8; ++t) {
                    int jt = j + t;
                    int c  = __builtin_amdgcn_readlane(mc, jt);
                    int vb = __builtin_amdgcn_readlane(mvb, jt);
                    bool ok = jt < rem;
                    c    = ok ? c : 0;
                    v[t] = ok ? __builtin_bit_cast(float, vb) : 0.f;
                    g[t] = *(const unsigned*)(base + (((unsigned)c) << 8) + (lane << 2));
                }
                #pragma unroll
                for (int t = 0; t < 8; ++t) {
                    ax[t & 3] += v[t] * bfl(g[t]);
                    ay[t & 3] += v[t] * bfh(g[t]);
                }
            }
        } else {
            int hf = lane >> 5, l = lane & 31;
            for (int j = 0; j < rem; j += 8) {
                unsigned g[4]; float v[4];
                #pragma unroll
                for (int t = 0; t < 4; ++t) {
                    int j0 = j + 2 * t, j1 = j0 + 1;
                    int c0 = __builtin_amdgcn_readlane(mc, j0);
                    int c1 = __builtin_amdgcn_readlane(mc, j1);
                    int w0 = __builtin_amdgcn_readlane(mvb, j0);
                    int w1 = __builtin_amdgcn_readlane(mvb, j1);
                    c0 = (j0 < rem) ? c0 : 0;
                    c1 = (j1 < rem) ? c1 : 0;
                    float f0 = (j0 < rem) ? __builtin_bit_cast(float, w0) : 0.f;
                    float f1 = (j1 < rem) ? __builtin_bit_cast(float, w1) : 0.f;
                    int c = hf ? c1 : c0;
                    v[t]  = hf ? f1 : f0;
                    g[t] = *(const unsigned*)(base + (((unsigned)c) << 7) + (l << 2));
                }
                #pragma unroll
                for (int t = 0; t < 4; ++t) {
                    ax[t] += v[t] * bfl(g[t]);
                    ay[t] += v[t] * bfh(g[t]);
                }
            }
        }
    }

    float sx = (ax[0] + ax[1]) + (ax[2] + ax[3]);
    float sy = (ay[0] + ay[1]) + (ay[2] + ay[3]);
    if (D == 64) {
        sx += __shfl_xor(sx, 32);
        sy += __shfl_xor(sy, 32);
    }
    int l = (D == 128) ? lane : (lane & 31);
    if (D == 128 || lane < 32) {
        float rx = sx + bias[2 * l], ry = sy + bias[2 * l + 1];
        rx = rx > 0.f ? rx : 0.f; ry = ry > 0.f ? ry : 0.f;
        ((unsigned*)(out + (size_t)node * out_stride))[l] = pkbf(rx, ry);
    }
}

// ---------------------------------------------------------------------------
// Fused head: out = log_softmax(x_cat[M,192](bf16) @ wlt[64,192]^T + bl).
// Same dbuf GEMM structure (BN=64, 512 thr); softmax 4 threads/row.
// ---------------------------------------------------------------------------
__global__ __launch_bounds__(512) void head_fused(const unsigned short* __restrict__ A,
                                                  const unsigned short* __restrict__ Bt,
                                                  const float* __restrict__ bl,
                                                  float* __restrict__ out, int M) {
    const int BKP = 40;
    const int MF = 2, NF = 2;            // wave tile 32x32, wr=wid>>1, wc=wid&1
    __shared__ unsigned short As[2][128 * BKP];
    __shared__ unsigned short Bs[2][64 * BKP];
    __shared__ float L[128][65];
    __shared__ float bls[NCLASS];

    int tid = threadIdx.x;
    int lane = tid & 63, wid = tid >> 6;
    int wr = wid >> 1, wc = wid & 1;
    int row0 = blockIdx.x * 128;
    if (tid < NCLASS) bls[tid] = bl[tid];

    f32x4 acc[MF][NF];
    #pragma unroll
    for (int i = 0; i < MF; ++i)
        #pragma unroll
        for (int j = 0; j < NF; ++j) acc[i][j] = f32x4{0.f, 0.f, 0.f, 0.f};

    uint4 arb, brg;
    auto LOAD = [&](int t) {
        int k0 = t * 32;
        int m = tid >> 2, k = (tid & 3) * 8;
        int row = row0 + m;
        arb = (row < M) ? *(const uint4*)(A + (size_t)row * 192 + k0 + k)
                        : uint4{0u, 0u, 0u, 0u};
        if (tid < 256) brg = *(const uint4*)(Bt + (size_t)m * 192 + k0 + k);
    };
    auto STORE = [&](int b) {
        int m = tid >> 2, k = (tid & 3) * 8;
        *(uint4*)&As[b][m * BKP + k] = arb;
        if (tid < 256) *(uint4*)&Bs[b][m * BKP + k] = brg;
    };

    const int NT = 6;                    // K = 192
    LOAD(0); STORE(0);
    __syncthreads();
    for (int t = 0; t < NT; ++t) {
        int cur = t & 1;
        if (t + 1 < NT) LOAD(t + 1);
        bf16x8 af[MF], bfr[NF];
        #pragma unroll
        for (int mi = 0; mi < MF; ++mi)
            af[mi] = *(const bf16x8*)&As[cur][(wr * 32 + mi * 16 + (lane & 15)) * BKP + (lane >> 4) * 8];
        #pragma unroll
        for (int ni = 0; ni < NF; ++ni)
            bfr[ni] = *(const bf16x8*)&Bs[cur][(wc * 32 + ni * 16 + (lane & 15)) * BKP + (lane >> 4) * 8];
        #pragma unroll
        for (int mi = 0; mi < MF; ++mi)
            #pragma unroll
            for (int ni = 0; ni < NF; ++ni)
                acc[mi][ni] = __builtin_amdgcn_mfma_f32_16x16x32_bf16(af[mi], bfr[ni], acc[mi][ni], 0, 0, 0);
        if (t + 1 < NT) {
            STORE(cur ^ 1);
            __syncthreads();
        }
    }

    #pragma unroll
    for (int mi = 0; mi < MF; ++mi) {
        int rt = wr * 32 + mi * 16 + ((lane >> 4) << 2);
        #pragma unroll
        for (int ni = 0; ni < NF; ++ni) {
            int ct = wc * 32 + ni * 16 + (lane & 15);
            #pragma unroll
            for (int r = 0; r < 4; ++r) L[rt + r][ct] = acc[mi][ni][r];
        }
    }
    __syncthreads();

    // softmax: 4 threads per row, 10 classes each, shfl combine
    {
        int r = tid >> 2, h = tid & 3;
        int row = row0 + r;
        if (row < M) {
            float vals[10];
            float m = -1e30f;
            #pragma unroll
            for (int c = 0; c < 10; ++c) {
                float tv = L[r][h * 10 + c] + bls[h * 10 + c];
                vals[c] = tv;
                m = fmaxf(m, tv);
            }
            m = fmaxf(m, __shfl_xor(m, 1));
            m = fmaxf(m, __shfl_xor(m, 2));
            float s = 0.f;
            #pragma unroll
            for (int c = 0; c < 10; ++c) s += __expf(vals[c] - m);
            s += __shfl_xor(s, 1);
            s += __shfl_xor(s, 2);
            float lg = __logf(s);
            float* o = out + (size_t)row * NCLASS + h * 10;
            #pragma unroll
            for (int c = 0; c < 10; ++c) o[c] = vals[c] - m - lg;
        }
    }
}

// ---------------------------------------------------------------------------
extern "C" void kernel_launch(void* const* d_in, const int* in_sizes, int n_in,
                              void* d_out, int out_size, void* d_ws, size_t ws_size,
                              hipStream_t stream) {
    const float* x        = (const float*)d_in[0];
    const int*   edge_row = (const int*)d_in[1];
    const int*   edge_col = (const int*)d_in[2];
    const float* edge_val = (const float*)d_in[3];
    const float* w1       = (const float*)d_in[4];
    const float* b1       = (const float*)d_in[5];
    const float* w2       = (const float*)d_in[6];
    const float* b2       = (const float*)d_in[7];
    const float* wl       = (const float*)d_in[8];
    const float* bl       = (const float*)d_in[9];
    float* out = (float*)d_out;
    (void)in_sizes; (void)n_in; (void)out_size; (void)ws_size;

    char* ws = (char*)d_ws;
    size_t off = 0;
    int* row_ptr = (int*)(ws + off);
    off += (((size_t)(N_NODES + 1) * sizeof(int)) + 255) & ~(size_t)255;
    unsigned short* x_cat = (unsigned short*)(ws + off);
    off += (size_t)N_NODES * 192 * sizeof(short);
    unsigned short* sup = (unsigned short*)(ws + off);
    off += (size_t)N_NODES * NHID * sizeof(short);
    unsigned short* w1t = (unsigned short*)(ws + off); off += (size_t)NHID * NFEAT * sizeof(short);
    unsigned short* w2t = (unsigned short*)(ws + off); off += (size_t)NHID2 * NHID * sizeof(short);
    unsigned short* wlt = (unsigned short*)(ws + off); off += (size_t)NCLS_P * 192 * sizeof(short);

    unsigned short* x1 = x_cat + NHID2;   // cols 64..191, stride 192
    unsigned short* x2 = x_cat;           // cols 0..63,   stride 192

    prep<<<(PREP_T3 + 255) / 256, 256, 0, stream>>>(edge_row, row_ptr, w1, w1t, w2, w2t, wl, wlt);

    int mblocks = (N_NODES + 127) / 128;

    // layer 1
    gemm_bf16<NHID, 0, 1><<<dim3(mblocks, 1), 512, 0, stream>>>(x, w1t, sup, N_NODES, NFEAT, NFEAT);
    spmm_bias_relu<NHID><<<(N_NODES + 3) / 4, 256, 0, stream>>>(
        sup, row_ptr, edge_col, edge_val, b1, x1, 192, N_NODES);

    // layer 2
    gemm_bf16<NHID2, 1, 1><<<dim3(mblocks, 1), 512, 0, stream>>>(x1, w2t, sup, N_NODES, NHID, 192);
    spmm_bias_relu<NHID2><<<(N_NODES + 3) / 4, 256, 0, stream>>>(
        sup, row_ptr, edge_col, edge_val, b2, x2, 192, N_NODES);

    // fused head
    head_fused<<<dim3(mblocks, 1), 512, 0, stream>>>(x_cat, wlt, bl, out, N_NODES);
}

// Round 8
// 167.075 us; speedup vs baseline: 3.9934x; 1.0617x over previous
//
#include <hip/hip_runtime.h>
#include <math.h>

#define N_NODES 100000
#define N_EDGES 1600000
#define NFEAT   256
#define NHID    128
#define NHID2   64
#define NCLASS  40
#define NCLS_P  64

typedef __attribute__((ext_vector_type(8))) short bf16x8;
typedef __attribute__((ext_vector_type(4))) float f32x4;
typedef __attribute__((ext_vector_type(2))) float f32x2;

static __device__ inline unsigned short f2bf(float f) {
    union { float f; unsigned u; } v; v.f = f;
    unsigned r = v.u + 0x7FFF + ((v.u >> 16) & 1);   // RNE
    return (unsigned short)(r >> 16);
}
static __device__ inline unsigned pkbf(float a, float b) {   // packed bf16x2
    return (unsigned)f2bf(a) | ((unsigned)f2bf(b) << 16);
}
static __device__ inline float bfl(unsigned u) {             // low bf16 -> f32
    union { unsigned u; float f; } v; v.u = u << 16; return v.f;
}
static __device__ inline float bfraw(unsigned u) {           // high bf16 -> f32 (low mantissa garbage, rel err <= 2^-9)
    union { unsigned u; float f; } v; v.u = u; return v.f;
}

// ---------------------------------------------------------------------------
// Merged prep: CSR row_ptr + 3 weight transposes + packed edge meta {col,val}.
// ---------------------------------------------------------------------------
#define PREP_T0 (N_NODES + 1)
#define PREP_T1 (PREP_T0 + NHID * NFEAT)
#define PREP_T2 (PREP_T1 + NHID2 * NHID)
#define PREP_T3 (PREP_T2 + NCLS_P * 192)
#define PREP_T4 (PREP_T3 + N_EDGES)
__global__ void prep(const int* __restrict__ er, int* __restrict__ row_ptr,
                     const float* __restrict__ w1, unsigned short* __restrict__ w1t,
                     const float* __restrict__ w2, unsigned short* __restrict__ w2t,
                     const float* __restrict__ wl, unsigned short* __restrict__ wlt,
                     const int* __restrict__ ec, const float* __restrict__ ev,
                     uint2* __restrict__ meta) {
    int idx = blockIdx.x * blockDim.x + threadIdx.x;
    if (idx < PREP_T0) {
        int lo = 0, hi = N_EDGES;
        while (lo < hi) { int mid = (lo + hi) >> 1; if (er[mid] < idx) lo = mid + 1; else hi = mid; }
        row_ptr[idx] = lo;
    } else if (idx < PREP_T1) {
        int i = idx - PREP_T0;          // w1t[n][k]: n<128, k<256
        int n = i >> 8, k = i & 255;
        w1t[i] = f2bf(w1[k * NHID + n]);
    } else if (idx < PREP_T2) {
        int i = idx - PREP_T1;          // w2t[n][k]: n<64, k<128
        int n = i >> 7, k = i & 127;
        w2t[i] = f2bf(w2[k * NHID2 + n]);
    } else if (idx < PREP_T3) {
        int i = idx - PREP_T2;          // wlt[n][k]: n<64 (pad>=40 -> 0), k<192
        int n = i / 192, k = i - n * 192;
        wlt[i] = (n < NCLASS) ? f2bf(wl[k * NCLASS + n]) : (unsigned short)0;
    } else if (idx < PREP_T4) {
        int i = idx - PREP_T3;
        uint2 m; m.x = (unsigned)ec[i];
        union { float f; unsigned u; } v; v.f = ev[i];
        m.y = v.u;
        meta[i] = m;
    }
}

// ---------------------------------------------------------------------------
// bf16 MFMA GEMM: C[M,BN] = A[M,K] @ Bt[BN,K]^T.
// BM=128, BK=32, 512 threads (8 waves), reg-staged double-buffered LDS.
// ---------------------------------------------------------------------------
template <int BN, int ABF16, int CBF16>
__global__ __launch_bounds__(512) void gemm_bf16(const void* __restrict__ A,
                                                 const unsigned short* __restrict__ Bt,
                                                 void* __restrict__ C,
                                                 int M, int K, int lda) {
    const int BKP = 40;
    const int WC = (BN == 128) ? 4 : 2;
    const int WR = 8 / WC;
    const int MF = (128 / WR) / 16;
    const int NF = (BN / WC) / 16;
    __shared__ unsigned short As[2][128 * BKP];
    __shared__ unsigned short Bs[2][BN * BKP];

    int tid = threadIdx.x;
    int lane = tid & 63, wid = tid >> 6;
    int wr = wid / WC, wc = wid % WC;
    int row0 = blockIdx.x * 128;

    f32x4 acc[MF][NF];
    #pragma unroll
    for (int i = 0; i < MF; ++i)
        #pragma unroll
        for (int j = 0; j < NF; ++j) acc[i][j] = f32x4{0.f, 0.f, 0.f, 0.f};

    float4 arf[2]; uint4 arb; uint4 brg;

    auto LOAD = [&](int t) {
        int k0 = t * 32;
        if (ABF16) {
            const unsigned short* Ab = (const unsigned short*)A;
            int m = tid >> 2, k = (tid & 3) * 8;
            int row = row0 + m;
            arb = (row < M) ? *(const uint4*)(Ab + (size_t)row * lda + k0 + k)
                            : uint4{0u, 0u, 0u, 0u};
        } else {
            const float* Af = (const float*)A;
            #pragma unroll
            for (int i = 0; i < 2; ++i) {
                int s = tid + i * 512;
                int m = s >> 3, k = (s & 7) * 4;
                int row = row0 + m;
                arf[i] = (row < M) ? *(const float4*)(Af + (size_t)row * lda + k0 + k)
                                   : float4{0.f, 0.f, 0.f, 0.f};
            }
        }
        if (BN == 128 || tid < 256) {
            int n = tid >> 2, k = (tid & 3) * 8;
            brg = *(const uint4*)(Bt + (size_t)n * K + k0 + k);
        }
    };
    auto STORE = [&](int b) {
        if (ABF16) {
            int m = tid >> 2, k = (tid & 3) * 8;
            *(uint4*)&As[b][m * BKP + k] = arb;
        } else {
            #pragma unroll
            for (int i = 0; i < 2; ++i) {
                int s = tid + i * 512;
                int m = s >> 3, k = (s & 7) * 4;
                uint2 p; p.x = pkbf(arf[i].x, arf[i].y); p.y = pkbf(arf[i].z, arf[i].w);
                *(uint2*)&As[b][m * BKP + k] = p;
            }
        }
        if (BN == 128 || tid < 256) {
            int n = tid >> 2, k = (tid & 3) * 8;
            *(uint4*)&Bs[b][n * BKP + k] = brg;
        }
    };

    const int NT = K / 32;
    LOAD(0); STORE(0);
    __syncthreads();
    for (int t = 0; t < NT; ++t) {
        int cur = t & 1;
        if (t + 1 < NT) LOAD(t + 1);
        bf16x8 af[MF], bfr[NF];
        #pragma unroll
        for (int mi = 0; mi < MF; ++mi)
            af[mi] = *(const bf16x8*)&As[cur][(wr * (MF * 16) + mi * 16 + (lane & 15)) * BKP + (lane >> 4) * 8];
        #pragma unroll
        for (int ni = 0; ni < NF; ++ni)
            bfr[ni] = *(const bf16x8*)&Bs[cur][(wc * (NF * 16) + ni * 16 + (lane & 15)) * BKP + (lane >> 4) * 8];
        #pragma unroll
        for (int mi = 0; mi < MF; ++mi)
            #pragma unroll
            for (int ni = 0; ni < NF; ++ni)
                acc[mi][ni] = __builtin_amdgcn_mfma_f32_16x16x32_bf16(af[mi], bfr[ni], acc[mi][ni], 0, 0, 0);
        if (t + 1 < NT) {
            STORE(cur ^ 1);
            __syncthreads();
        }
    }

    #pragma unroll
    for (int mi = 0; mi < MF; ++mi) {
        int rbase = row0 + wr * (MF * 16) + mi * 16 + ((lane >> 4) << 2);
        #pragma unroll
        for (int ni = 0; ni < NF; ++ni) {
            int col = wc * (NF * 16) + ni * 16 + (lane & 15);
            #pragma unroll
            for (int r = 0; r < 4; ++r) {
                int row = rbase + r;
                if (row < M) {
                    if (CBF16) ((unsigned short*)C)[(size_t)row * BN + col] = f2bf(acc[mi][ni][r]);
                    else       ((float*)C)[(size_t)row * BN + col] = acc[mi][ni][r];
                }
            }
        }
    }
}

// ---------------------------------------------------------------------------
// SpMM (CSR, one wave per dst node) + bias + relu. bf16 storage, f32 acc.
// Metadata staged in per-wave LDS (ds_read_b64 broadcast, no readlane).
// Sub-group edges: D=128 -> 2 edges/instr (half-wave, dwordx2 = 4ch/lane);
// D=64 -> 4 edges/instr (quarter-wave). 8 gathers in flight. High bf16
// consumed as raw bitcast (rel err <= 2^-9); low via lshl. float2 FMA.
// Tail edges padded {0,0} at staging (row 0 stays hot, v=0).
// ---------------------------------------------------------------------------
template <int D>
__global__ __launch_bounds__(256) void spmm_bias_relu(const unsigned short* __restrict__ sup,
                                                      const int* __restrict__ row_ptr,
                                                      const uint2* __restrict__ meta,
                                                      const float* __restrict__ bias,
                                                      unsigned short* __restrict__ out,
                                                      int out_stride, int n_nodes) {
    const int EPG   = (D == 128) ? 2 : 4;     // edges per gather group
    const int JSTEP = 8 * EPG;                // 8 gathers in flight
    const int SHIFT = (D == 128) ? 8 : 7;     // row byte-stride log2

    __shared__ uint2 mlds[4][64];

    int wave = threadIdx.x >> 6;
    int lane = threadIdx.x & 63;
    int node = blockIdx.x * 4 + wave;
    if (node >= n_nodes) return;

    int sub = (D == 128) ? (lane >> 5) : (lane >> 4);   // edge slot in group
    int l   = (D == 128) ? (lane & 31) : (lane & 15);   // channel lane (4 ch)

    int e0 = row_ptr[node];
    int cnt = row_ptr[node + 1] - e0;
    const char* base = (const char*)sup;
    unsigned loff = (unsigned)(l << 3);

    f32x2 a0 = {0.f, 0.f}, a1 = {0.f, 0.f};

    for (int o = 0; o < cnt; o += 64) {
        int rem = min(64, cnt - o);
        uint2 m;
        if (lane < rem) m = meta[e0 + o + lane];
        else { m.x = 0u; m.y = 0u; }
        mlds[wave][lane] = m;          // wave-private region; lgkmcnt ordering

        for (int j = 0; j < rem; j += JSTEP) {
            uint2 g[8]; float vv[8];
            #pragma unroll
            for (int t = 0; t < 8; ++t) {
                uint2 cm = mlds[wave][j + t * EPG + sub];
                unsigned voff = (cm.x << SHIFT) + loff;
                g[t] = *(const uint2*)(base + voff);
                union { unsigned u; float f; } c; c.u = cm.y;
                vv[t] = c.f;
            }
            #pragma unroll
            for (int t = 0; t < 8; ++t) {
                f32x2 v2 = {vv[t], vv[t]};
                f32x2 f0 = {bfl(g[t].x), bfraw(g[t].x)};
                f32x2 f1 = {bfl(g[t].y), bfraw(g[t].y)};
                a0 += v2 * f0;
                a1 += v2 * f1;
            }
        }
    }

    // combine sub-group partials
    a0.x += __shfl_xor(a0.x, 32); a0.y += __shfl_xor(a0.y, 32);
    a1.x += __shfl_xor(a1.x, 32); a1.y += __shfl_xor(a1.y, 32);
    if (D == 64) {
        a0.x += __shfl_xor(a0.x, 16); a0.y += __shfl_xor(a0.y, 16);
        a1.x += __shfl_xor(a1.x, 16); a1.y += __shfl_xor(a1.y, 16);
    }

    if (lane < ((D == 128) ? 32 : 16)) {
        float4 bv = *(const float4*)(bias + 4 * l);
        float r0 = a0.x + bv.x, r1 = a0.y + bv.y;
        float r2 = a1.x + bv.z, r3 = a1.y + bv.w;
        r0 = r0 > 0.f ? r0 : 0.f; r1 = r1 > 0.f ? r1 : 0.f;
        r2 = r2 > 0.f ? r2 : 0.f; r3 = r3 > 0.f ? r3 : 0.f;
        uint2 pk; pk.x = pkbf(r0, r1); pk.y = pkbf(r2, r3);
        *(uint2*)(out + (size_t)node * out_stride + 4 * l) = pk;
    }
}

// ---------------------------------------------------------------------------
// Fused head: out = log_softmax(x_cat[M,192](bf16) @ wlt[64,192]^T + bl).
// ---------------------------------------------------------------------------
__global__ __launch_bounds__(512) void head_fused(const unsigned short* __restrict__ A,
                                                  const unsigned short* __restrict__ Bt,
                                                  const float* __restrict__ bl,
                                                  float* __restrict__ out, int M) {
    const int BKP = 40;
    const int MF = 2, NF = 2;
    __shared__ unsigned short As[2][128 * BKP];
    __shared__ unsigned short Bs[2][64 * BKP];
    __shared__ float L[128][65];
    __shared__ float bls[NCLASS];

    int tid = threadIdx.x;
    int lane = tid & 63, wid = tid >> 6;
    int wr = wid >> 1, wc = wid & 1;
    int row0 = blockIdx.x * 128;
    if (tid < NCLASS) bls[tid] = bl[tid];

    f32x4 acc[MF][NF];
    #pragma unroll
    for (int i = 0; i < MF; ++i)
        #pragma unroll
        for (int j = 0; j < NF; ++j) acc[i][j] = f32x4{0.f, 0.f, 0.f, 0.f};

    uint4 arb, brg;
    auto LOAD = [&](int t) {
        int k0 = t * 32;
        int m = tid >> 2, k = (tid & 3) * 8;
        int row = row0 + m;
        arb = (row < M) ? *(const uint4*)(A + (size_t)row * 192 + k0 + k)
                        : uint4{0u, 0u, 0u, 0u};
        if (tid < 256) brg = *(const uint4*)(Bt + (size_t)m * 192 + k0 + k);
    };
    auto STORE = [&](int b) {
        int m = tid >> 2, k = (tid & 3) * 8;
        *(uint4*)&As[b][m * BKP + k] = arb;
        if (tid < 256) *(uint4*)&Bs[b][m * BKP + k] = brg;
    };

    const int NT = 6;                    // K = 192
    LOAD(0); STORE(0);
    __syncthreads();
    for (int t = 0; t < NT; ++t) {
        int cur = t & 1;
        if (t + 1 < NT) LOAD(t + 1);
        bf16x8 af[MF], bfr[NF];
        #pragma unroll
        for (int mi = 0; mi < MF; ++mi)
            af[mi] = *(const bf16x8*)&As[cur][(wr * 32 + mi * 16 + (lane & 15)) * BKP + (lane >> 4) * 8];
        #pragma unroll
        for (int ni = 0; ni < NF; ++ni)
            bfr[ni] = *(const bf16x8*)&Bs[cur][(wc * 32 + ni * 16 + (lane & 15)) * BKP + (lane >> 4) * 8];
        #pragma unroll
        for (int mi = 0; mi < MF; ++mi)
            #pragma unroll
            for (int ni = 0; ni < NF; ++ni)
                acc[mi][ni] = __builtin_amdgcn_mfma_f32_16x16x32_bf16(af[mi], bfr[ni], acc[mi][ni], 0, 0, 0);
        if (t + 1 < NT) {
            STORE(cur ^ 1);
            __syncthreads();
        }
    }

    #pragma unroll
    for (int mi = 0; mi < MF; ++mi) {
        int rt = wr * 32 + mi * 16 + ((lane >> 4) << 2);
        #pragma unroll
        for (int ni = 0; ni < NF; ++ni) {
            int ct = wc * 32 + ni * 16 + (lane & 15);
            #pragma unroll
            for (int r = 0; r < 4; ++r) L[rt + r][ct] = acc[mi][ni][r];
        }
    }
    __syncthreads();

    {
        int r = tid >> 2, h = tid & 3;
        int row = row0 + r;
        if (row < M) {
            float vals[10];
            float m = -1e30f;
            #pragma unroll
            for (int c = 0; c < 10; ++c) {
                float tv = L[r][h * 10 + c] + bls[h * 10 + c];
                vals[c] = tv;
                m = fmaxf(m, tv);
            }
            m = fmaxf(m, __shfl_xor(m, 1));
            m = fmaxf(m, __shfl_xor(m, 2));
            float s = 0.f;
            #pragma unroll
            for (int c = 0; c < 10; ++c) s += __expf(vals[c] - m);
            s += __shfl_xor(s, 1);
            s += __shfl_xor(s, 2);
            float lg = __logf(s);
            float* o = out + (size_t)row * NCLASS + h * 10;
            #pragma unroll
            for (int c = 0; c < 10; ++c) o[c] = vals[c] - m - lg;
        }
    }
}

// ---------------------------------------------------------------------------
extern "C" void kernel_launch(void* const* d_in, const int* in_sizes, int n_in,
                              void* d_out, int out_size, void* d_ws, size_t ws_size,
                              hipStream_t stream) {
    const float* x        = (const float*)d_in[0];
    const int*   edge_row = (const int*)d_in[1];
    const int*   edge_col = (const int*)d_in[2];
    const float* edge_val = (const float*)d_in[3];
    const float* w1       = (const float*)d_in[4];
    const float* b1       = (const float*)d_in[5];
    const float* w2       = (const float*)d_in[6];
    const float* b2       = (const float*)d_in[7];
    const float* wl       = (const float*)d_in[8];
    const float* bl       = (const float*)d_in[9];
    float* out = (float*)d_out;
    (void)in_sizes; (void)n_in; (void)out_size; (void)ws_size;

    char* ws = (char*)d_ws;
    size_t off = 0;
    int* row_ptr = (int*)(ws + off);
    off += (((size_t)(N_NODES + 1) * sizeof(int)) + 255) & ~(size_t)255;
    unsigned short* x_cat = (unsigned short*)(ws + off);
    off += (size_t)N_NODES * 192 * sizeof(short);
    unsigned short* sup = (unsigned short*)(ws + off);
    off += (size_t)N_NODES * NHID * sizeof(short);
    uint2* meta = (uint2*)(ws + off);   off += (size_t)N_EDGES * sizeof(uint2);
    unsigned short* w1t = (unsigned short*)(ws + off); off += (size_t)NHID * NFEAT * sizeof(short);
    unsigned short* w2t = (unsigned short*)(ws + off); off += (size_t)NHID2 * NHID * sizeof(short);
    unsigned short* wlt = (unsigned short*)(ws + off); off += (size_t)NCLS_P * 192 * sizeof(short);

    unsigned short* x1 = x_cat + NHID2;   // cols 64..191, stride 192
    unsigned short* x2 = x_cat;           // cols 0..63,   stride 192

    prep<<<(PREP_T4 + 255) / 256, 256, 0, stream>>>(edge_row, row_ptr, w1, w1t, w2, w2t, wl, wlt,
                                                    edge_col, edge_val, meta);

    int mblocks = (N_NODES + 127) / 128;

    // layer 1
    gemm_bf16<NHID, 0, 1><<<dim3(mblocks, 1), 512, 0, stream>>>(x, w1t, sup, N_NODES, NFEAT, NFEAT);
    spmm_bias_relu<NHID><<<(N_NODES + 3) / 4, 256, 0, stream>>>(
        sup, row_ptr, meta, b1, x1, 192, N_NODES);

    // layer 2
    gemm_bf16<NHID2, 1, 1><<<dim3(mblocks, 1), 512, 0, stream>>>(x1, w2t, sup, N_NODES, NHID, 192);
    spmm_bias_relu<NHID2><<<(N_NODES + 3) / 4, 256, 0, stream>>>(
        sup, row_ptr, meta, b2, x2, 192, N_NODES);

    // fused head
    head_fused<<<dim3(mblocks, 1), 512, 0, stream>>>(x_cat, wlt, bl, out, N_NODES);
}

// Round 10
// 163.385 us; speedup vs baseline: 4.0836x; 1.0226x over previous
//
#include <hip/hip_runtime.h>
#include <math.h>

#define N_NODES 100000
#define N_EDGES 1600000
#define NFEAT   256
#define NHID    128
#define NHID2   64
#define NCLASS  40
#define NCLS_P  64

typedef __attribute__((ext_vector_type(8))) short bf16x8;
typedef __attribute__((ext_vector_type(4))) float f32x4;
typedef __attribute__((ext_vector_type(2))) float f32x2;

static __device__ inline unsigned short f2bf(float f) {
    union { float f; unsigned u; } v; v.f = f;
    unsigned r = v.u + 0x7FFF + ((v.u >> 16) & 1);   // RNE
    return (unsigned short)(r >> 16);
}
static __device__ inline unsigned pkbf(float a, float b) {   // packed bf16x2
    return (unsigned)f2bf(a) | ((unsigned)f2bf(b) << 16);
}
static __device__ inline float bfl(unsigned u) {             // low bf16 -> f32
    union { unsigned u; float f; } v; v.u = u << 16; return v.f;
}
static __device__ inline float bfraw(unsigned u) {           // high bf16 -> f32 (low mantissa garbage)
    union { unsigned u; float f; } v; v.u = u; return v.f;
}

// ---- fp8 e4m3 pack/unpack: HW cvt if available, bitwise fallback ----------
#if __has_builtin(__builtin_amdgcn_cvt_pk_fp8_f32) && __has_builtin(__builtin_amdgcn_cvt_pk_f32_fp8)
#define FP8_HW 1
#else
#define FP8_HW 0
static __device__ inline unsigned f2fp8_sw(float f) {        // e4m3fn, RNE, FTZ below 2^-6
    union { float f; unsigned u; } v; v.f = f;
    unsigned s = (v.u >> 24) & 0x80u;
    int e = (int)((v.u >> 23) & 0xFF) - 120;                 // fp8 exp field
    unsigned m = v.u & 0x7FFFFFu;
    if (e < 1) return s;                                     // flush tiny to 0
    unsigned keep = m >> 20, rest = m & 0xFFFFFu;
    keep += (rest > 0x80000u) || (rest == 0x80000u && (keep & 1));
    if (keep == 8) { keep = 0; ++e; }
    if (e > 15) { e = 15; keep = 6; }                        // clamp to 448
    return s | ((unsigned)e << 3) | keep;
}
static __device__ inline float fp8f_sw(unsigned b) {
    unsigned e = (b >> 3) & 0xF;
    union { unsigned u; float f; } v;
    v.u = ((b & 0x80u) << 24) | ((e + 120) << 23) | ((b & 7u) << 20);
    return e ? v.f : 0.f;
}
#endif

static __device__ inline unsigned pack4_fp8(float a, float b, float c, float d) {
#if FP8_HW
    int r = __builtin_amdgcn_cvt_pk_fp8_f32(a, b, 0, false);
    r = __builtin_amdgcn_cvt_pk_fp8_f32(c, d, r, true);
    return (unsigned)r;
#else
    return f2fp8_sw(a) | (f2fp8_sw(b) << 8) | (f2fp8_sw(c) << 16) | (f2fp8_sw(d) << 24);
#endif
}
static __device__ inline void unpack4_fp8(unsigned g, f32x2& lo, f32x2& hi) {
#if FP8_HW
    lo = __builtin_amdgcn_cvt_pk_f32_fp8((int)g, false);
    hi = __builtin_amdgcn_cvt_pk_f32_fp8((int)g, true);
#else
    lo.x = fp8f_sw(g & 0xFF); lo.y = fp8f_sw((g >> 8) & 0xFF);
    hi.x = fp8f_sw((g >> 16) & 0xFF); hi.y = fp8f_sw(g >> 24);
#endif
}

// ---------------------------------------------------------------------------
// Merged prep: CSR row_ptr + 3 weight transposes + packed edge meta {col,val}.
// ---------------------------------------------------------------------------
#define PREP_T0 (N_NODES + 1)
#define PREP_T1 (PREP_T0 + NHID * NFEAT)
#define PREP_T2 (PREP_T1 + NHID2 * NHID)
#define PREP_T3 (PREP_T2 + NCLS_P * 192)
#define PREP_T4 (PREP_T3 + N_EDGES)
__global__ void prep(const int* __restrict__ er, int* __restrict__ row_ptr,
                     const float* __restrict__ w1, unsigned short* __restrict__ w1t,
                     const float* __restrict__ w2, unsigned short* __restrict__ w2t,
                     const float* __restrict__ wl, unsigned short* __restrict__ wlt,
                     const int* __restrict__ ec, const float* __restrict__ ev,
                     uint2* __restrict__ meta) {
    int idx = blockIdx.x * blockDim.x + threadIdx.x;
    if (idx < PREP_T0) {
        int lo = 0, hi = N_EDGES;
        while (lo < hi) { int mid = (lo + hi) >> 1; if (er[mid] < idx) lo = mid + 1; else hi = mid; }
        row_ptr[idx] = lo;
    } else if (idx < PREP_T1) {
        int i = idx - PREP_T0;          // w1t[n][k]: n<128, k<256
        int n = i >> 8, k = i & 255;
        w1t[i] = f2bf(w1[k * NHID + n]);
    } else if (idx < PREP_T2) {
        int i = idx - PREP_T1;          // w2t[n][k]: n<64, k<128
        int n = i >> 7, k = i & 127;
        w2t[i] = f2bf(w2[k * NHID2 + n]);
    } else if (idx < PREP_T3) {
        int i = idx - PREP_T2;          // wlt[n][k]: n<64 (pad>=40 -> 0), k<192
        int n = i / 192, k = i - n * 192;
        wlt[i] = (n < NCLASS) ? f2bf(wl[k * NCLASS + n]) : (unsigned short)0;
    } else if (idx < PREP_T4) {
        int i = idx - PREP_T3;
        uint2 m; m.x = (unsigned)ec[i];
        union { float f; unsigned u; } v; v.f = ev[i];
        m.y = v.u;
        meta[i] = m;
    }
}

// ---------------------------------------------------------------------------
// bf16 sup -> fp8 e4m3 sup8 (streaming convert, 8 elems/thread).
// ---------------------------------------------------------------------------
__global__ __launch_bounds__(256) void conv_fp8(const uint4* __restrict__ sup16,
                                                uint2* __restrict__ sup8, int nw) {
    int i = blockIdx.x * blockDim.x + threadIdx.x;
    if (i >= nw) return;
    uint4 s = sup16[i];
    uint2 r;
    r.x = pack4_fp8(bfl(s.x), bfraw(s.x), bfl(s.y), bfraw(s.y));
    r.y = pack4_fp8(bfl(s.z), bfraw(s.z), bfl(s.w), bfraw(s.w));
    sup8[i] = r;
}

// ---------------------------------------------------------------------------
// bf16 MFMA GEMM: C[M,BN] = A[M,K] @ Bt[BN,K]^T.
// BM=128, BK=32, 512 threads (8 waves). Depth-2 register prefetch into
// double-buffered LDS: LOAD(t+3) issued at iter t, one barrier per step.
// K is a template param -> loop fully unrolls, bank indices static.
// ---------------------------------------------------------------------------
template <int BN, int K, int ABF16, int CBF16>
__global__ __launch_bounds__(512) void gemm_bf16(const void* __restrict__ A,
                                                 const unsigned short* __restrict__ Bt,
                                                 void* __restrict__ C,
                                                 int M, int lda) {
    const int BKP = 40;
    const int NT = K / 32;
    const int WC = (BN == 128) ? 4 : 2;
    const int WR = 8 / WC;
    const int MF = (128 / WR) / 16;
    const int NF = (BN / WC) / 16;
    __shared__ unsigned short As[2][128 * BKP];
    __shared__ unsigned short Bs[2][BN * BKP];

    int tid = threadIdx.x;
    int lane = tid & 63, wid = tid >> 6;
    int wr = wid / WC, wc = wid % WC;
    int row0 = blockIdx.x * 128;

    f32x4 acc[MF][NF];
    #pragma unroll
    for (int i = 0; i < MF; ++i)
        #pragma unroll
        for (int j = 0; j < NF; ++j) acc[i][j] = f32x4{0.f, 0.f, 0.f, 0.f};

    float4 arf[2][2]; uint4 arb[2]; uint4 brg[2];

    auto LOAD = [&](int t, int b) {
        int k0 = t * 32;
        if (ABF16) {
            const unsigned short* Ab = (const unsigned short*)A;
            int m = tid >> 2, k = (tid & 3) * 8;
            int row = row0 + m;
            arb[b] = (row < M) ? *(const uint4*)(Ab + (size_t)row * lda + k0 + k)
                               : uint4{0u, 0u, 0u, 0u};
        } else {
            const float* Af = (const float*)A;
            #pragma unroll
            for (int i = 0; i < 2; ++i) {
                int s = tid + i * 512;
                int m = s >> 3, k = (s & 7) * 4;
                int row = row0 + m;
                arf[b][i] = (row < M) ? *(const float4*)(Af + (size_t)row * lda + k0 + k)
                                      : float4{0.f, 0.f, 0.f, 0.f};
            }
        }
        if (BN == 128 || tid < 256) {
            int n = tid >> 2, k = (tid & 3) * 8;
            brg[b] = *(const uint4*)(Bt + (size_t)n * K + k0 + k);
        }
    };
    auto STORE = [&](int t, int b) {
        int buf = t & 1;
        if (ABF16) {
            int m = tid >> 2, k = (tid & 3) * 8;
            *(uint4*)&As[buf][m * BKP + k] = arb[b];
        } else {
            #pragma unroll
            for (int i = 0; i < 2; ++i) {
                int s = tid + i * 512;
                int m = s >> 3, k = (s & 7) * 4;
                uint2 p; p.x = pkbf(arf[b][i].x, arf[b][i].y); p.y = pkbf(arf[b][i].z, arf[b][i].w);
                *(uint2*)&As[buf][m * BKP + k] = p;
            }
        }
        if (BN == 128 || tid < 256) {
            int n = tid >> 2, k = (tid & 3) * 8;
            *(uint4*)&Bs[buf][n * BKP + k] = brg[b];
        }
    };

    LOAD(0, 0); STORE(0, 0); LOAD(1, 1);
    if (NT > 2) LOAD(2, 0);
    __syncthreads();

    #pragma unroll
    for (int t = 0; t < NT; ++t) {
        int cur = t & 1;
        bf16x8 af[MF], bfr[NF];
        #pragma unroll
        for (int mi = 0; mi < MF; ++mi)
            af[mi] = *(const bf16x8*)&As[cur][(wr * (MF * 16) + mi * 16 + (lane & 15)) * BKP + (lane >> 4) * 8];
        #pragma unroll
        for (int ni = 0; ni < NF; ++ni)
            bfr[ni] = *(const bf16x8*)&Bs[cur][(wc * (NF * 16) + ni * 16 + (lane & 15)) * BKP + (lane >> 4) * 8];
        #pragma unroll
        for (int mi = 0; mi < MF; ++mi)
            #pragma unroll
            for (int ni = 0; ni < NF; ++ni)
                acc[mi][ni] = __builtin_amdgcn_mfma_f32_16x16x32_bf16(af[mi], bfr[ni], acc[mi][ni], 0, 0, 0);
        if (t + 1 < NT) {
            STORE(t + 1, (t + 1) & 1);
            if (t + 3 < NT) LOAD(t + 3, (t + 1) & 1);
            __syncthreads();
        }
    }

    #pragma unroll
    for (int mi = 0; mi < MF; ++mi) {
        int rbase = row0 + wr * (MF * 16) + mi * 16 + ((lane >> 4) << 2);
        #pragma unroll
        for (int ni = 0; ni < NF; ++ni) {
            int col = wc * (NF * 16) + ni * 16 + (lane & 15);
            #pragma unroll
            for (int r = 0; r < 4; ++r) {
                int row = rbase + r;
                if (row < M) {
                    if (CBF16) ((unsigned short*)C)[(size_t)row * BN + col] = f2bf(acc[mi][ni][r]);
                    else       ((float*)C)[(size_t)row * BN + col] = acc[mi][ni][r];
                }
            }
        }
    }
}

// ---------------------------------------------------------------------------
// Layer-1 SpMM over fp8 sup8[node][128] (128B/row) + bias + relu -> bf16 out.
// One wave per dst node; meta via LDS broadcast; half-wave per edge
// (32 lanes x 4B = 128B row), 8 gathers (16 edges) in flight. f32 acc.
// ---------------------------------------------------------------------------
__global__ __launch_bounds__(256) void spmm_fp8(const unsigned char* __restrict__ sup8,
                                                const int* __restrict__ row_ptr,
                                                const uint2* __restrict__ meta,
                                                const float* __restrict__ bias,
                                                unsigned short* __restrict__ out,
                                                int out_stride, int n_nodes) {
    __shared__ uint2 mlds[4][64];

    int wave = threadIdx.x >> 6;
    int lane = threadIdx.x & 63;
    int node = blockIdx.x * 4 + wave;
    if (node >= n_nodes) return;

    int sub = lane >> 5, l = lane & 31;
    int e0 = row_ptr[node];
    int cnt = row_ptr[node + 1] - e0;
    unsigned loff = (unsigned)(l << 2);

    f32x2 a0 = {0.f, 0.f}, a1 = {0.f, 0.f};

    for (int o = 0; o < cnt; o += 64) {
        int rem = min(64, cnt - o);
        uint2 m;
        if (lane < rem) m = meta[e0 + o + lane];
        else { m.x = 0u; m.y = 0u; }
        mlds[wave][lane] = m;

        for (int j = 0; j < rem; j += 16) {
            unsigned g[8]; float vv[8];
            #pragma unroll
            for (int t = 0; t < 8; ++t) {
                uint2 cm = mlds[wave][j + 2 * t + sub];
                g[t] = *(const unsigned*)(sup8 + (((size_t)cm.x) << 7) + loff);
                union { unsigned u; float f; } c; c.u = cm.y;
                vv[t] = c.f;
            }
            #pragma unroll
            for (int t = 0; t < 8; ++t) {
                f32x2 lo, hi;
                unpack4_fp8(g[t], lo, hi);
                f32x2 v2 = {vv[t], vv[t]};
                a0 += v2 * lo;
                a1 += v2 * hi;
            }
        }
    }

    a0.x += __shfl_xor(a0.x, 32); a0.y += __shfl_xor(a0.y, 32);
    a1.x += __shfl_xor(a1.x, 32); a1.y += __shfl_xor(a1.y, 32);

    if (lane < 32) {
        float4 bv = *(const float4*)(bias + 4 * l);
        float r0 = a0.x + bv.x, r1 = a0.y + bv.y;
        float r2 = a1.x + bv.z, r3 = a1.y + bv.w;
        r0 = r0 > 0.f ? r0 : 0.f; r1 = r1 > 0.f ? r1 : 0.f;
        r2 = r2 > 0.f ? r2 : 0.f; r3 = r3 > 0.f ? r3 : 0.f;
        uint2 pk; pk.x = pkbf(r0, r1); pk.y = pkbf(r2, r3);
        *(uint2*)(out + (size_t)node * out_stride + 4 * l) = pk;
    }
}

// ---------------------------------------------------------------------------
// Layer-2 SpMM (bf16 sup, D=64) + bias + relu. Quarter-wave per edge.
// ---------------------------------------------------------------------------
__global__ __launch_bounds__(256) void spmm_bf16_64(const unsigned short* __restrict__ sup,
                                                    const int* __restrict__ row_ptr,
                                                    const uint2* __restrict__ meta,
                                                    const float* __restrict__ bias,
                                                    unsigned short* __restrict__ out,
                                                    int out_stride, int n_nodes) {
    __shared__ uint2 mlds[4][64];

    int wave = threadIdx.x >> 6;
    int lane = threadIdx.x & 63;
    int node = blockIdx.x * 4 + wave;
    if (node >= n_nodes) return;

    int sub = lane >> 4, l = lane & 15;
    int e0 = row_ptr[node];
    int cnt = row_ptr[node + 1] - e0;
    const char* base = (const char*)sup;
    unsigned loff = (unsigned)(l << 3);

    f32x2 a0 = {0.f, 0.f}, a1 = {0.f, 0.f};

    for (int o = 0; o < cnt; o += 64) {
        int rem = min(64, cnt - o);
        uint2 m;
        if (lane < rem) m = meta[e0 + o + lane];
        else { m.x = 0u; m.y = 0u; }
        mlds[wave][lane] = m;

        for (int j = 0; j < rem; j += 32) {
            uint2 g[8]; float vv[8];
            #pragma unroll
            for (int t = 0; t < 8; ++t) {
                uint2 cm = mlds[wave][j + 4 * t + sub];
                unsigned voff = (cm.x << 7) + loff;
                g[t] = *(const uint2*)(base + voff);
                union { unsigned u; float f; } c; c.u = cm.y;
                vv[t] = c.f;
            }
            #pragma unroll
            for (int t = 0; t < 8; ++t) {
                f32x2 v2 = {vv[t], vv[t]};
                f32x2 f0 = {bfl(g[t].x), bfraw(g[t].x)};
                f32x2 f1 = {bfl(g[t].y), bfraw(g[t].y)};
                a0 += v2 * f0;
                a1 += v2 * f1;
            }
        }
    }

    a0.x += __shfl_xor(a0.x, 32); a0.y += __shfl_xor(a0.y, 32);
    a1.x += __shfl_xor(a1.x, 32); a1.y += __shfl_xor(a1.y, 32);
    a0.x += __shfl_xor(a0.x, 16); a0.y += __shfl_xor(a0.y, 16);
    a1.x += __shfl_xor(a1.x, 16); a1.y += __shfl_xor(a1.y, 16);

    if (lane < 16) {
        float4 bv = *(const float4*)(bias + 4 * l);
        float r0 = a0.x + bv.x, r1 = a0.y + bv.y;
        float r2 = a1.x + bv.z, r3 = a1.y + bv.w;
        r0 = r0 > 0.f ? r0 : 0.f; r1 = r1 > 0.f ? r1 : 0.f;
        r2 = r2 > 0.f ? r2 : 0.f; r3 = r3 > 0.f ? r3 : 0.f;
        uint2 pk; pk.x = pkbf(r0, r1); pk.y = pkbf(r2, r3);
        *(uint2*)(out + (size_t)node * out_stride + 4 * l) = pk;
    }
}

// ---------------------------------------------------------------------------
// Fused head: out = log_softmax(x_cat[M,192](bf16) @ wlt[64,192]^T + bl).
// ---------------------------------------------------------------------------
__global__ __launch_bounds__(512) void head_fused(const unsigned short* __restrict__ A,
                                                  const unsigned short* __restrict__ Bt,
                                                  const float* __restrict__ bl,
                                                  float* __restrict__ out, int M) {
    const int BKP = 40;
    const int MF = 2, NF = 2;
    __shared__ unsigned short As[2][128 * BKP];
    __shared__ unsigned short Bs[2][64 * BKP];
    __shared__ float L[128][65];
    __shared__ float bls[NCLASS];

    int tid = threadIdx.x;
    int lane = tid & 63, wid = tid >> 6;
    int wr = wid >> 1, wc = wid & 1;
    int row0 = blockIdx.x * 128;
    if (tid < NCLASS) bls[tid] = bl[tid];

    f32x4 acc[MF][NF];
    #pragma unroll
    for (int i = 0; i < MF; ++i)
        #pragma unroll
        for (int j = 0; j < NF; ++j) acc[i][j] = f32x4{0.f, 0.f, 0.f, 0.f};

    uint4 arb, brg;
    auto LOAD = [&](int t) {
        int k0 = t * 32;
        int m = tid >> 2, k = (tid & 3) * 8;
        int row = row0 + m;
        arb = (row < M) ? *(const uint4*)(A + (size_t)row * 192 + k0 + k)
                        : uint4{0u, 0u, 0u, 0u};
        if (tid < 256) brg = *(const uint4*)(Bt + (size_t)m * 192 + k0 + k);
    };
    auto STORE = [&](int b) {
        int m = tid >> 2, k = (tid & 3) * 8;
        *(uint4*)&As[b][m * BKP + k] = arb;
        if (tid < 256) *(uint4*)&Bs[b][m * BKP + k] = brg;
    };

    const int NT = 6;                    // K = 192
    LOAD(0); STORE(0);
    __syncthreads();
    #pragma unroll
    for (int t = 0; t < NT; ++t) {
        int cur = t & 1;
        if (t + 1 < NT) LOAD(t + 1);
        bf16x8 af[MF], bfr[NF];
        #pragma unroll
        for (int mi = 0; mi < MF; ++mi)
            af[mi] = *(const bf16x8*)&As[cur][(wr * 32 + mi * 16 + (lane & 15)) * BKP + (lane >> 4) * 8];
        #pragma unroll
        for (int ni = 0; ni < NF; ++ni)
            bfr[ni] = *(const bf16x8*)&Bs[cur][(wc * 32 + ni * 16 + (lane & 15)) * BKP + (lane >> 4) * 8];
        #pragma unroll
        for (int mi = 0; mi < MF; ++mi)
            #pragma unroll
            for (int ni = 0; ni < NF; ++ni)
                acc[mi][ni] = __builtin_amdgcn_mfma_f32_16x16x32_bf16(af[mi], bfr[ni], acc[mi][ni], 0, 0, 0);
        if (t + 1 < NT) {
            STORE(cur ^ 1);
            __syncthreads();
        }
    }

    #pragma unroll
    for (int mi = 0; mi < MF; ++mi) {
        int rt = wr * 32 + mi * 16 + ((lane >> 4) << 2);
        #pragma unroll
        for (int ni = 0; ni < NF; ++ni) {
            int ct = wc * 32 + ni * 16 + (lane & 15);
            #pragma unroll
            for (int r = 0; r < 4; ++r) L[rt + r][ct] = acc[mi][ni][r];
        }
    }
    __syncthreads();

    {
        int r = tid >> 2, h = tid & 3;
        int row = row0 + r;
        if (row < M) {
            float vals[10];
            float m = -1e30f;
            #pragma unroll
            for (int c = 0; c < 10; ++c) {
                float tv = L[r][h * 10 + c] + bls[h * 10 + c];
                vals[c] = tv;
                m = fmaxf(m, tv);
            }
            m = fmaxf(m, __shfl_xor(m, 1));
            m = fmaxf(m, __shfl_xor(m, 2));
            float s = 0.f;
            #pragma unroll
            for (int c = 0; c < 10; ++c) s += __expf(vals[c] - m);
            s += __shfl_xor(s, 1);
            s += __shfl_xor(s, 2);
            float lg = __logf(s);
            float* o = out + (size_t)row * NCLASS + h * 10;
            #pragma unroll
            for (int c = 0; c < 10; ++c) o[c] = vals[c] - m - lg;
        }
    }
}

// ---------------------------------------------------------------------------
extern "C" void kernel_launch(void* const* d_in, const int* in_sizes, int n_in,
                              void* d_out, int out_size, void* d_ws, size_t ws_size,
                              hipStream_t stream) {
    const float* x        = (const float*)d_in[0];
    const int*   edge_row = (const int*)d_in[1];
    const int*   edge_col = (const int*)d_in[2];
    const float* edge_val = (const float*)d_in[3];
    const float* w1       = (const float*)d_in[4];
    const float* b1       = (const float*)d_in[5];
    const float* w2       = (const float*)d_in[6];
    const float* b2       = (const float*)d_in[7];
    const float* wl       = (const float*)d_in[8];
    const float* bl       = (const float*)d_in[9];
    float* out = (float*)d_out;
    (void)in_sizes; (void)n_in; (void)out_size; (void)ws_size;

    char* ws = (char*)d_ws;
    size_t off = 0;
    int* row_ptr = (int*)(ws + off);
    off += (((size_t)(N_NODES + 1) * sizeof(int)) + 255) & ~(size_t)255;
    unsigned short* x_cat = (unsigned short*)(ws + off);
    off += (size_t)N_NODES * 192 * sizeof(short);
    unsigned short* sup = (unsigned short*)(ws + off);        // bf16: layer1 [N][128], reused layer2 [N][64]
    off += (size_t)N_NODES * NHID * sizeof(short);
    unsigned char* sup8 = (unsigned char*)(ws + off);         // fp8 copy of layer-1 sup
    off += (size_t)N_NODES * NHID;
    uint2* meta = (uint2*)(ws + off);   off += (size_t)N_EDGES * sizeof(uint2);
    unsigned short* w1t = (unsigned short*)(ws + off); off += (size_t)NHID * NFEAT * sizeof(short);
    unsigned short* w2t = (unsigned short*)(ws + off); off += (size_t)NHID2 * NHID * sizeof(short);
    unsigned short* wlt = (unsigned short*)(ws + off); off += (size_t)NCLS_P * 192 * sizeof(short);

    unsigned short* x1 = x_cat + NHID2;   // cols 64..191, stride 192
    unsigned short* x2 = x_cat;           // cols 0..63,   stride 192

    prep<<<(PREP_T4 + 255) / 256, 256, 0, stream>>>(edge_row, row_ptr, w1, w1t, w2, w2t, wl, wlt,
                                                    edge_col, edge_val, meta);

    int mblocks = (N_NODES + 127) / 128;

    // layer 1: sup(bf16) = x @ w1; sup8 = fp8(sup); x1 = relu(spmm(sup8) + b1)
    gemm_bf16<NHID, NFEAT, 0, 1><<<dim3(mblocks, 1), 512, 0, stream>>>(x, w1t, sup, N_NODES, NFEAT);
    conv_fp8<<<(N_NODES * NHID / 8 + 255) / 256, 256, 0, stream>>>((const uint4*)sup, (uint2*)sup8,
                                                                   N_NODES * NHID / 8);
    spmm_fp8<<<(N_NODES + 3) / 4, 256, 0, stream>>>(sup8, row_ptr, meta, b1, x1, 192, N_NODES);

    // layer 2: sup2(bf16) = x1 @ w2; x2 = relu(spmm(sup2) + b2)
    gemm_bf16<NHID2, NHID, 1, 1><<<dim3(mblocks, 1), 512, 0, stream>>>(x1, w2t, sup, N_NODES, 192);
    spmm_bf16_64<<<(N_NODES + 3) / 4, 256, 0, stream>>>(sup, row_ptr, meta, b2, x2, 192, N_NODES);

    // fused head
    head_fused<<<dim3(mblocks, 1), 512, 0, stream>>>(x_cat, wlt, bl, out, N_NODES);
}

// Round 11
// 151.107 us; speedup vs baseline: 4.4154x; 1.0812x over previous
//
#include <hip/hip_runtime.h>
#include <math.h>

#define N_NODES 100000
#define N_EDGES 1600000
#define NFEAT   256
#define NHID    128
#define NHID2   64
#define NCLASS  40
#define NCLS_P  64

typedef __attribute__((ext_vector_type(8))) short bf16x8;
typedef __attribute__((ext_vector_type(4))) float f32x4;
typedef __attribute__((ext_vector_type(2))) float f32x2;

static __device__ inline unsigned short f2bf(float f) {
    union { float f; unsigned u; } v; v.f = f;
    unsigned r = v.u + 0x7FFF + ((v.u >> 16) & 1);   // RNE
    return (unsigned short)(r >> 16);
}
static __device__ inline unsigned pkbf(float a, float b) {   // packed bf16x2
    return (unsigned)f2bf(a) | ((unsigned)f2bf(b) << 16);
}
static __device__ inline float bfl(unsigned u) {             // low bf16 -> f32
    union { unsigned u; float f; } v; v.u = u << 16; return v.f;
}
static __device__ inline float bfraw(unsigned u) {           // high bf16 -> f32 (low mantissa garbage)
    union { unsigned u; float f; } v; v.u = u; return v.f;
}

// ---- fp8 e4m3 pack/unpack: HW cvt if available, bitwise fallback ----------
#if __has_builtin(__builtin_amdgcn_cvt_pk_fp8_f32) && __has_builtin(__builtin_amdgcn_cvt_pk_f32_fp8)
#define FP8_HW 1
#else
#define FP8_HW 0
static __device__ inline unsigned f2fp8_sw(float f) {        // e4m3fn, RNE, FTZ below 2^-6
    union { float f; unsigned u; } v; v.f = f;
    unsigned s = (v.u >> 24) & 0x80u;
    int e = (int)((v.u >> 23) & 0xFF) - 120;                 // fp8 exp field
    unsigned m = v.u & 0x7FFFFFu;
    if (e < 1) return s;                                     // flush tiny to 0
    unsigned keep = m >> 20, rest = m & 0xFFFFFu;
    keep += (rest > 0x80000u) || (rest == 0x80000u && (keep & 1));
    if (keep == 8) { keep = 0; ++e; }
    if (e > 15) { e = 15; keep = 6; }                        // clamp to 448
    return s | ((unsigned)e << 3) | keep;
}
static __device__ inline float fp8f_sw(unsigned b) {
    unsigned e = (b >> 3) & 0xF;
    union { unsigned u; float f; } v;
    v.u = ((b & 0x80u) << 24) | ((e + 120) << 23) | ((b & 7u) << 20);
    return e ? v.f : 0.f;
}
#endif

static __device__ inline unsigned pack4_fp8(float a, float b, float c, float d) {
#if FP8_HW
    int r = __builtin_amdgcn_cvt_pk_fp8_f32(a, b, 0, false);
    r = __builtin_amdgcn_cvt_pk_fp8_f32(c, d, r, true);
    return (unsigned)r;
#else
    return f2fp8_sw(a) | (f2fp8_sw(b) << 8) | (f2fp8_sw(c) << 16) | (f2fp8_sw(d) << 24);
#endif
}
static __device__ inline void unpack4_fp8(unsigned g, f32x2& lo, f32x2& hi) {
#if FP8_HW
    lo = __builtin_amdgcn_cvt_pk_f32_fp8((int)g, false);
    hi = __builtin_amdgcn_cvt_pk_f32_fp8((int)g, true);
#else
    lo.x = fp8f_sw(g & 0xFF); lo.y = fp8f_sw((g >> 8) & 0xFF);
    hi.x = fp8f_sw((g >> 16) & 0xFF); hi.y = fp8f_sw(g >> 24);
#endif
}

// ---------------------------------------------------------------------------
// Merged prep: CSR row_ptr + 3 weight transposes + packed edge meta {col,val}.
// ---------------------------------------------------------------------------
#define PREP_T0 (N_NODES + 1)
#define PREP_T1 (PREP_T0 + NHID * NFEAT)
#define PREP_T2 (PREP_T1 + NHID2 * NHID)
#define PREP_T3 (PREP_T2 + NCLS_P * 192)
#define PREP_T4 (PREP_T3 + N_EDGES)
__global__ void prep(const int* __restrict__ er, int* __restrict__ row_ptr,
                     const float* __restrict__ w1, unsigned short* __restrict__ w1t,
                     const float* __restrict__ w2, unsigned short* __restrict__ w2t,
                     const float* __restrict__ wl, unsigned short* __restrict__ wlt,
                     const int* __restrict__ ec, const float* __restrict__ ev,
                     uint2* __restrict__ meta) {
    int idx = blockIdx.x * blockDim.x + threadIdx.x;
    if (idx < PREP_T0) {
        int lo = 0, hi = N_EDGES;
        while (lo < hi) { int mid = (lo + hi) >> 1; if (er[mid] < idx) lo = mid + 1; else hi = mid; }
        row_ptr[idx] = lo;
    } else if (idx < PREP_T1) {
        int i = idx - PREP_T0;          // w1t[n][k]: n<128, k<256
        int n = i >> 8, k = i & 255;
        w1t[i] = f2bf(w1[k * NHID + n]);
    } else if (idx < PREP_T2) {
        int i = idx - PREP_T1;          // w2t[n][k]: n<64, k<128
        int n = i >> 7, k = i & 127;
        w2t[i] = f2bf(w2[k * NHID2 + n]);
    } else if (idx < PREP_T3) {
        int i = idx - PREP_T2;          // wlt[n][k]: n<64 (pad>=40 -> 0), k<192
        int n = i / 192, k = i - n * 192;
        wlt[i] = (n < NCLASS) ? f2bf(wl[k * NCLASS + n]) : (unsigned short)0;
    } else if (idx < PREP_T4) {
        int i = idx - PREP_T3;
        uint2 m; m.x = (unsigned)ec[i];
        union { float f; unsigned u; } v; v.f = ev[i];
        m.y = v.u;
        meta[i] = m;
    }
}

// ---------------------------------------------------------------------------
// Single-phase full-K MFMA GEMM: C[M,BN] = A[M,K] @ Bt[BN,K]^T.
// BM=128, 512 threads (8 waves). The ENTIRE K-panel (A and B) is staged into
// dynamic LDS once -> ONE vmcnt drain + ONE barrier, then a barrier-free MFMA
// loop. LDS row stride K+8 elems => 528/272/400 B == 4 dwords (mod 32) =>
// fragment ds_read_b128 spreads all 32 banks (8 dw/bank, zero excess).
// CMODE: 1 = bf16 strided (ldc), 2 = fp8 packed via LDS repack (BN=128 only).
// ---------------------------------------------------------------------------
template <int BN, int K, int ABF16, int CMODE>
__global__ __launch_bounds__(512) void gemm_full(const void* __restrict__ A,
                                                 const unsigned short* __restrict__ Bt,
                                                 void* __restrict__ C,
                                                 int M, int lda, int ldc) {
    const int S   = K + 8;               // LDS row stride (bf16 elems)
    const int OCT = K / 8;               // bf16 octets per row
    const int WC  = (BN == 128) ? 4 : 2;
    const int MF  = (BN == 128) ? 4 : 2; // 128/(8/WC)/16
    const int NF  = 2;                   // (BN/WC)/16
    const int NT  = K / 32;

    extern __shared__ char smem[];
    unsigned short* As = (unsigned short*)smem;           // [128][S]
    unsigned short* Bs = As + 128 * S;                    // [BN][S]

    int tid = threadIdx.x;
    int lane = tid & 63, wid = tid >> 6;
    int wr = wid / WC, wc = wid % WC;
    int row0 = blockIdx.x * 128;

    // ---- stage A (full K panel) ----
    if (ABF16) {
        const unsigned short* Ab = (const unsigned short*)A;
        const int NI = 128 * OCT / 512;
        uint4 av[NI];
        #pragma unroll
        for (int i = 0; i < NI; ++i) {
            int s = tid + i * 512;
            int m = s / OCT, kk = (s - m * OCT) * 8;
            int row = row0 + m;
            av[i] = (row < M) ? *(const uint4*)(Ab + (size_t)row * lda + kk)
                              : uint4{0u, 0u, 0u, 0u};
        }
        #pragma unroll
        for (int i = 0; i < NI; ++i) {
            int s = tid + i * 512;
            int m = s / OCT, kk = (s - m * OCT) * 8;
            *(uint4*)&As[m * S + kk] = av[i];
        }
    } else {
        const float* Af = (const float*)A;
        const int NI = 128 * (K / 4) / 512;   // float4 slots per thread (K=256 -> 16)
        float4 av[NI];
        #pragma unroll
        for (int i = 0; i < NI; ++i) {
            int s = tid + i * 512;
            int m = s / (K / 4), c = (s - m * (K / 4)) * 4;
            int row = row0 + m;
            av[i] = (row < M) ? *(const float4*)(Af + (size_t)row * lda + c)
                              : float4{0.f, 0.f, 0.f, 0.f};
        }
        #pragma unroll
        for (int i = 0; i < NI; ++i) {
            int s = tid + i * 512;
            int m = s / (K / 4), c = (s - m * (K / 4)) * 4;
            uint2 p; p.x = pkbf(av[i].x, av[i].y); p.y = pkbf(av[i].z, av[i].w);
            *(uint2*)&As[m * S + c] = p;
        }
    }
    // ---- stage B (full K panel) ----
    {
        const int NI = BN * OCT / 512;
        uint4 bv[NI];
        #pragma unroll
        for (int i = 0; i < NI; ++i) {
            int s = tid + i * 512;
            int n = s / OCT, kk = (s - n * OCT) * 8;
            bv[i] = *(const uint4*)(Bt + (size_t)n * K + kk);
        }
        #pragma unroll
        for (int i = 0; i < NI; ++i) {
            int s = tid + i * 512;
            int n = s / OCT, kk = (s - n * OCT) * 8;
            *(uint4*)&Bs[n * S + kk] = bv[i];
        }
    }
    __syncthreads();

    // ---- barrier-free MFMA loop over the staged panel ----
    f32x4 acc[MF][NF];
    #pragma unroll
    for (int i = 0; i < MF; ++i)
        #pragma unroll
        for (int j = 0; j < NF; ++j) acc[i][j] = f32x4{0.f, 0.f, 0.f, 0.f};

    #pragma unroll
    for (int t = 0; t < NT; ++t) {
        bf16x8 af[MF], bfr[NF];
        #pragma unroll
        for (int mi = 0; mi < MF; ++mi)
            af[mi] = *(const bf16x8*)&As[(wr * (MF * 16) + mi * 16 + (lane & 15)) * S + t * 32 + (lane >> 4) * 8];
        #pragma unroll
        for (int ni = 0; ni < NF; ++ni)
            bfr[ni] = *(const bf16x8*)&Bs[(wc * (NF * 16) + ni * 16 + (lane & 15)) * S + t * 32 + (lane >> 4) * 8];
        #pragma unroll
        for (int mi = 0; mi < MF; ++mi)
            #pragma unroll
            for (int ni = 0; ni < NF; ++ni)
                acc[mi][ni] = __builtin_amdgcn_mfma_f32_16x16x32_bf16(af[mi], bfr[ni], acc[mi][ni], 0, 0, 0);
    }

    if (CMODE == 1) {
        // direct bf16 strided stores
        #pragma unroll
        for (int mi = 0; mi < MF; ++mi) {
            int rbase = row0 + wr * (MF * 16) + mi * 16 + ((lane >> 4) << 2);
            #pragma unroll
            for (int ni = 0; ni < NF; ++ni) {
                int col = wc * (NF * 16) + ni * 16 + (lane & 15);
                #pragma unroll
                for (int r = 0; r < 4; ++r) {
                    int row = rbase + r;
                    if (row < M)
                        ((unsigned short*)C)[(size_t)row * ldc + col] = f2bf(acc[mi][ni][r]);
                }
            }
        }
    } else {
        // fp8 packed output via LDS repack (BN==128): acc -> f32 LDS -> 32B/thread
        __syncthreads();                       // done reading As
        float* Lf = (float*)As;                // [128][132] f32 (67584 B == As size)
        const int LS = 132;
        #pragma unroll
        for (int mi = 0; mi < MF; ++mi) {
            int rt = wr * (MF * 16) + mi * 16 + ((lane >> 4) << 2);
            #pragma unroll
            for (int ni = 0; ni < NF; ++ni) {
                int ct = wc * (NF * 16) + ni * 16 + (lane & 15);
                #pragma unroll
                for (int r = 0; r < 4; ++r) Lf[(rt + r) * LS + ct] = acc[mi][ni][r];
            }
        }
        __syncthreads();
        int rl = tid >> 2, c0 = (tid & 3) * 32;
        int row = row0 + rl;
        if (row < M) {
            unsigned u[8];
            #pragma unroll
            for (int q = 0; q < 8; ++q) {
                f32x4 v = *(const f32x4*)&Lf[rl * LS + c0 + q * 4];
                u[q] = pack4_fp8(v[0], v[1], v[2], v[3]);
            }
            unsigned char* o = (unsigned char*)C + (size_t)row * 128 + c0;
            *(uint4*)o = uint4{u[0], u[1], u[2], u[3]};
            *(uint4*)(o + 16) = uint4{u[4], u[5], u[6], u[7]};
        }
    }
}

// ---------------------------------------------------------------------------
// Layer-1 SpMM over fp8 sup8[node][128] (128B/row) + bias + relu -> bf16 out.
// ---------------------------------------------------------------------------
__global__ __launch_bounds__(256) void spmm_fp8(const unsigned char* __restrict__ sup8,
                                                const int* __restrict__ row_ptr,
                                                const uint2* __restrict__ meta,
                                                const float* __restrict__ bias,
                                                unsigned short* __restrict__ out,
                                                int out_stride, int n_nodes) {
    __shared__ uint2 mlds[4][64];

    int wave = threadIdx.x >> 6;
    int lane = threadIdx.x & 63;
    int node = blockIdx.x * 4 + wave;
    if (node >= n_nodes) return;

    int sub = lane >> 5, l = lane & 31;
    int e0 = row_ptr[node];
    int cnt = row_ptr[node + 1] - e0;
    unsigned loff = (unsigned)(l << 2);

    f32x2 a0 = {0.f, 0.f}, a1 = {0.f, 0.f};

    for (int o = 0; o < cnt; o += 64) {
        int rem = min(64, cnt - o);
        uint2 m;
        if (lane < rem) m = meta[e0 + o + lane];
        else { m.x = 0u; m.y = 0u; }
        mlds[wave][lane] = m;

        for (int j = 0; j < rem; j += 16) {
            unsigned g[8]; float vv[8];
            #pragma unroll
            for (int t = 0; t < 8; ++t) {
                uint2 cm = mlds[wave][j + 2 * t + sub];
                g[t] = *(const unsigned*)(sup8 + (((size_t)cm.x) << 7) + loff);
                union { unsigned u; float f; } c; c.u = cm.y;
                vv[t] = c.f;
            }
            #pragma unroll
            for (int t = 0; t < 8; ++t) {
                f32x2 lo, hi;
                unpack4_fp8(g[t], lo, hi);
                f32x2 v2 = {vv[t], vv[t]};
                a0 += v2 * lo;
                a1 += v2 * hi;
            }
        }
    }

    a0.x += __shfl_xor(a0.x, 32); a0.y += __shfl_xor(a0.y, 32);
    a1.x += __shfl_xor(a1.x, 32); a1.y += __shfl_xor(a1.y, 32);

    if (lane < 32) {
        float4 bv = *(const float4*)(bias + 4 * l);
        float r0 = a0.x + bv.x, r1 = a0.y + bv.y;
        float r2 = a1.x + bv.z, r3 = a1.y + bv.w;
        r0 = r0 > 0.f ? r0 : 0.f; r1 = r1 > 0.f ? r1 : 0.f;
        r2 = r2 > 0.f ? r2 : 0.f; r3 = r3 > 0.f ? r3 : 0.f;
        uint2 pk; pk.x = pkbf(r0, r1); pk.y = pkbf(r2, r3);
        *(uint2*)(out + (size_t)node * out_stride + 4 * l) = pk;
    }
}

// ---------------------------------------------------------------------------
// Layer-2 SpMM (bf16 sup, D=64) + bias + relu. Quarter-wave per edge.
// ---------------------------------------------------------------------------
__global__ __launch_bounds__(256) void spmm_bf16_64(const unsigned short* __restrict__ sup,
                                                    const int* __restrict__ row_ptr,
                                                    const uint2* __restrict__ meta,
                                                    const float* __restrict__ bias,
                                                    unsigned short* __restrict__ out,
                                                    int out_stride, int n_nodes) {
    __shared__ uint2 mlds[4][64];

    int wave = threadIdx.x >> 6;
    int lane = threadIdx.x & 63;
    int node = blockIdx.x * 4 + wave;
    if (node >= n_nodes) return;

    int sub = lane >> 4, l = lane & 15;
    int e0 = row_ptr[node];
    int cnt = row_ptr[node + 1] - e0;
    const char* base = (const char*)sup;
    unsigned loff = (unsigned)(l << 3);

    f32x2 a0 = {0.f, 0.f}, a1 = {0.f, 0.f};

    for (int o = 0; o < cnt; o += 64) {
        int rem = min(64, cnt - o);
        uint2 m;
        if (lane < rem) m = meta[e0 + o + lane];
        else { m.x = 0u; m.y = 0u; }
        mlds[wave][lane] = m;

        for (int j = 0; j < rem; j += 32) {
            uint2 g[8]; float vv[8];
            #pragma unroll
            for (int t = 0; t < 8; ++t) {
                uint2 cm = mlds[wave][j + 4 * t + sub];
                unsigned voff = (cm.x << 7) + loff;
                g[t] = *(const uint2*)(base + voff);
                union { unsigned u; float f; } c; c.u = cm.y;
                vv[t] = c.f;
            }
            #pragma unroll
            for (int t = 0; t < 8; ++t) {
                f32x2 v2 = {vv[t], vv[t]};
                f32x2 f0 = {bfl(g[t].x), bfraw(g[t].x)};
                f32x2 f1 = {bfl(g[t].y), bfraw(g[t].y)};
                a0 += v2 * f0;
                a1 += v2 * f1;
            }
        }
    }

    a0.x += __shfl_xor(a0.x, 32); a0.y += __shfl_xor(a0.y, 32);
    a1.x += __shfl_xor(a1.x, 32); a1.y += __shfl_xor(a1.y, 32);
    a0.x += __shfl_xor(a0.x, 16); a0.y += __shfl_xor(a0.y, 16);
    a1.x += __shfl_xor(a1.x, 16); a1.y += __shfl_xor(a1.y, 16);

    if (lane < 16) {
        float4 bv = *(const float4*)(bias + 4 * l);
        float r0 = a0.x + bv.x, r1 = a0.y + bv.y;
        float r2 = a1.x + bv.z, r3 = a1.y + bv.w;
        r0 = r0 > 0.f ? r0 : 0.f; r1 = r1 > 0.f ? r1 : 0.f;
        r2 = r2 > 0.f ? r2 : 0.f; r3 = r3 > 0.f ? r3 : 0.f;
        uint2 pk; pk.x = pkbf(r0, r1); pk.y = pkbf(r2, r3);
        *(uint2*)(out + (size_t)node * out_stride + 4 * l) = pk;
    }
}

// ---------------------------------------------------------------------------
// Fused head: out = log_softmax(x_cat[M,192](bf16) @ wlt[64,192]^T + bl).
// Single-phase full-K staging; logits via LDS; 4 threads/row softmax.
// ---------------------------------------------------------------------------
__global__ __launch_bounds__(512) void head_fused(const unsigned short* __restrict__ A,
                                                  const unsigned short* __restrict__ Bt,
                                                  const float* __restrict__ bl,
                                                  float* __restrict__ out, int M) {
    const int K = 192, S = K + 8, OCT = K / 8;   // 24
    const int MF = 2, NF = 2, NT = 6;

    extern __shared__ char smem[];
    unsigned short* As = (unsigned short*)smem;        // [128][200]
    unsigned short* Bs = As + 128 * S;                 // [64][200]
    float* L  = (float*)(Bs + 64 * S);                 // [128][65]
    float* bls = L + 128 * 65;                         // [40]

    int tid = threadIdx.x;
    int lane = tid & 63, wid = tid >> 6;
    int wr = wid >> 1, wc = wid & 1;
    int row0 = blockIdx.x * 128;
    if (tid < NCLASS) bls[tid] = bl[tid];

    // stage A: 128*24 octets / 512 = 6 per thread
    {
        uint4 av[6];
        #pragma unroll
        for (int i = 0; i < 6; ++i) {
            int s = tid + i * 512;
            int m = s / OCT, kk = (s - m * OCT) * 8;
            int row = row0 + m;
            av[i] = (row < M) ? *(const uint4*)(A + (size_t)row * 192 + kk)
                              : uint4{0u, 0u, 0u, 0u};
        }
        #pragma unroll
        for (int i = 0; i < 6; ++i) {
            int s = tid + i * 512;
            int m = s / OCT, kk = (s - m * OCT) * 8;
            *(uint4*)&As[m * S + kk] = av[i];
        }
    }
    // stage B: 64*24/512 = 3 per thread
    {
        uint4 bv[3];
        #pragma unroll
        for (int i = 0; i < 3; ++i) {
            int s = tid + i * 512;
            int n = s / OCT, kk = (s - n * OCT) * 8;
            bv[i] = *(const uint4*)(Bt + (size_t)n * 192 + kk);
        }
        #pragma unroll
        for (int i = 0; i < 3; ++i) {
            int s = tid + i * 512;
            int n = s / OCT, kk = (s - n * OCT) * 8;
            *(uint4*)&Bs[n * S + kk] = bv[i];
        }
    }
    __syncthreads();

    f32x4 acc[MF][NF];
    #pragma unroll
    for (int i = 0; i < MF; ++i)
        #pragma unroll
        for (int j = 0; j < NF; ++j) acc[i][j] = f32x4{0.f, 0.f, 0.f, 0.f};

    #pragma unroll
    for (int t = 0; t < NT; ++t) {
        bf16x8 af[MF], bfr[NF];
        #pragma unroll
        for (int mi = 0; mi < MF; ++mi)
            af[mi] = *(const bf16x8*)&As[(wr * 32 + mi * 16 + (lane & 15)) * S + t * 32 + (lane >> 4) * 8];
        #pragma unroll
        for (int ni = 0; ni < NF; ++ni)
            bfr[ni] = *(const bf16x8*)&Bs[(wc * 32 + ni * 16 + (lane & 15)) * S + t * 32 + (lane >> 4) * 8];
        #pragma unroll
        for (int mi = 0; mi < MF; ++mi)
            #pragma unroll
            for (int ni = 0; ni < NF; ++ni)
                acc[mi][ni] = __builtin_amdgcn_mfma_f32_16x16x32_bf16(af[mi], bfr[ni], acc[mi][ni], 0, 0, 0);
    }

    #pragma unroll
    for (int mi = 0; mi < MF; ++mi) {
        int rt = wr * 32 + mi * 16 + ((lane >> 4) << 2);
        #pragma unroll
        for (int ni = 0; ni < NF; ++ni) {
            int ct = wc * 32 + ni * 16 + (lane & 15);
            #pragma unroll
            for (int r = 0; r < 4; ++r) L[(rt + r) * 65 + ct] = acc[mi][ni][r];
        }
    }
    __syncthreads();

    {
        int r = tid >> 2, h = tid & 3;
        int row = row0 + r;
        if (row < M) {
            float vals[10];
            float m = -1e30f;
            #pragma unroll
            for (int c = 0; c < 10; ++c) {
                float tv = L[r * 65 + h * 10 + c] + bls[h * 10 + c];
                vals[c] = tv;
                m = fmaxf(m, tv);
            }
            m = fmaxf(m, __shfl_xor(m, 1));
            m = fmaxf(m, __shfl_xor(m, 2));
            float s = 0.f;
            #pragma unroll
            for (int c = 0; c < 10; ++c) s += __expf(vals[c] - m);
            s += __shfl_xor(s, 1);
            s += __shfl_xor(s, 2);
            float lg = __logf(s);
            float* o = out + (size_t)row * NCLASS + h * 10;
            #pragma unroll
            for (int c = 0; c < 10; ++c) o[c] = vals[c] - m - lg;
        }
    }
}

// ---------------------------------------------------------------------------
extern "C" void kernel_launch(void* const* d_in, const int* in_sizes, int n_in,
                              void* d_out, int out_size, void* d_ws, size_t ws_size,
                              hipStream_t stream) {
    const float* x        = (const float*)d_in[0];
    const int*   edge_row = (const int*)d_in[1];
    const int*   edge_col = (const int*)d_in[2];
    const float* edge_val = (const float*)d_in[3];
    const float* w1       = (const float*)d_in[4];
    const float* b1       = (const float*)d_in[5];
    const float* w2       = (const float*)d_in[6];
    const float* b2       = (const float*)d_in[7];
    const float* wl       = (const float*)d_in[8];
    const float* bl       = (const float*)d_in[9];
    float* out = (float*)d_out;
    (void)in_sizes; (void)n_in; (void)out_size; (void)ws_size;

    char* ws = (char*)d_ws;
    size_t off = 0;
    int* row_ptr = (int*)(ws + off);
    off += (((size_t)(N_NODES + 1) * sizeof(int)) + 255) & ~(size_t)255;
    unsigned short* x_cat = (unsigned short*)(ws + off);
    off += (size_t)N_NODES * 192 * sizeof(short);
    unsigned short* sup = (unsigned short*)(ws + off);        // bf16 layer-2 support [N][64]
    off += (size_t)N_NODES * NHID * sizeof(short);
    unsigned char* sup8 = (unsigned char*)(ws + off);         // fp8 layer-1 support [N][128]
    off += (size_t)N_NODES * NHID;
    uint2* meta = (uint2*)(ws + off);   off += (size_t)N_EDGES * sizeof(uint2);
    unsigned short* w1t = (unsigned short*)(ws + off); off += (size_t)NHID * NFEAT * sizeof(short);
    unsigned short* w2t = (unsigned short*)(ws + off); off += (size_t)NHID2 * NHID * sizeof(short);
    unsigned short* wlt = (unsigned short*)(ws + off); off += (size_t)NCLS_P * 192 * sizeof(short);

    unsigned short* x1 = x_cat + NHID2;   // cols 64..191, stride 192
    unsigned short* x2 = x_cat;           // cols 0..63,   stride 192

    prep<<<(PREP_T4 + 255) / 256, 256, 0, stream>>>(edge_row, row_ptr, w1, w1t, w2, w2t, wl, wlt,
                                                    edge_col, edge_val, meta);

    int mblocks = (N_NODES + 127) / 128;

    // dynamic LDS sizes
    const int smem1 = (128 + 128) * (NFEAT + 8) * 2;              // 135168
    const int smem2 = (128 + 64) * (NHID + 8) * 2;                // 52224
    const int smemH = (128 + 64) * (192 + 8) * 2 + 128 * 65 * 4 + NCLASS * 4;  // 110240

    // layer 1: sup8(fp8) = fp8(x @ w1); x1 = relu(spmm(sup8) + b1)
    gemm_full<NHID, NFEAT, 0, 2><<<dim3(mblocks, 1), 512, smem1, stream>>>(x, w1t, sup8, N_NODES, NFEAT, NHID);
    spmm_fp8<<<(N_NODES + 3) / 4, 256, 0, stream>>>(sup8, row_ptr, meta, b1, x1, 192, N_NODES);

    // layer 2: sup(bf16) = x1 @ w2; x2 = relu(spmm(sup) + b2)
    gemm_full<NHID2, NHID, 1, 1><<<dim3(mblocks, 1), 512, smem2, stream>>>(x1, w2t, sup, N_NODES, 192, NHID2);
    spmm_bf16_64<<<(N_NODES + 3) / 4, 256, 0, stream>>>(sup, row_ptr, meta, b2, x2, 192, N_NODES);

    // fused head
    head_fused<<<dim3(mblocks, 1), 512, smemH, stream>>>(x_cat, wlt, bl, out, N_NODES);
}